// Round 3
// baseline (13946.721 us; speedup 1.0000x reference)
//
#include <hip/hip_runtime.h>
#include <hip/hip_bf16.h>
#include <hip/hip_fp16.h>
#include <hip/hip_cooperative_groups.h>
#include <cmath>

namespace cg = cooperative_groups;
using bf16 = __hip_bfloat16;
typedef __attribute__((ext_vector_type(8))) short short8;
typedef __attribute__((ext_vector_type(4))) float floatx4;

__device__ __forceinline__ void lds_load16(void* lds, const void* g) {
  __builtin_amdgcn_global_load_lds(
      (const __attribute__((address_space(1))) void*)g,
      (__attribute__((address_space(3))) void*)lds, 16, 0, 0);
}

// ---------------- generic BT GEMM: C[M][N] = scale*(A[M][K] x B[N][K]^T) + bias ----------
struct GemmP {
  const bf16* A; const bf16* B;
  int M, N, K, lda, ldb;
  long sAimg, sAh, sBimg, sBh;
  int ZH, cross;
  float scale;
  const float* bias;
  float* Cf; int ldcf; long sCfImg, sCfH;
  bf16* Cb; int ldcb; long sCbImg, sCbH;
  __half* Ch; int ldch; long sChImg, sChH;
  const float* resid;  // fp32, same indexing as Cf
};

template <int NTILE>  // 128: 4 waves x (64x64); 64: 4 waves x (32x64)
__global__ __launch_bounds__(256, 2)
void gemm_bt(GemmP p) {
  __shared__ __align__(16) bf16 As[128 * 32];
  __shared__ __align__(16) bf16 Bs[NTILE * 32];
  constexpr int MI = (NTILE == 128) ? 4 : 2;
  const int z = blockIdx.z;
  const int imgA = z / p.ZH;
  const int h = z - imgA * p.ZH;
  const int imgB = imgA ^ p.cross;
  const bf16* Ab = p.A + (long)imgA * p.sAimg + (long)h * p.sAh;
  const bf16* Bb = p.B + (long)imgB * p.sBimg + (long)h * p.sBh;
  const int m0 = blockIdx.y * 128, n0 = blockIdx.x * NTILE;
  const int t = threadIdx.x, w = t >> 6, l = t & 63;
  const int lr = l >> 2, lk = (l & 3) * 8;   // staging: row-in-chunk, k-elem offset
  const int fr = l & 15, fk = (l >> 4) * 8;  // fragment: row-in-16tile, k offset

  const bf16* aG0 = Ab + (long)(m0 + w * 16 + lr) * p.lda + lk;
  const bf16* aG1 = aG0 + (long)64 * p.lda;
  const bf16* bG0 = Bb + (long)(n0 + w * 16 + lr) * p.ldb + lk;
  const bf16* bG1 = bG0 + (long)64 * p.ldb;
  bf16* aL0 = &As[w * 16 * 32];
  bf16* aL1 = &As[(w + 4) * 16 * 32];
  bf16* bL0 = &Bs[w * 16 * 32];
  bf16* bL1 = &Bs[(w + 4) * 16 * 32];
  const int wr = (NTILE == 128) ? (w >> 1) * 64 : w * 32;
  const int wc = (NTILE == 128) ? (w & 1) * 64 : 0;

  floatx4 zero4 = {0.f, 0.f, 0.f, 0.f};
  floatx4 acc[MI][4];
#pragma unroll
  for (int i = 0; i < MI; i++)
#pragma unroll
    for (int j = 0; j < 4; j++) acc[i][j] = zero4;

  for (int k0 = 0; k0 < p.K; k0 += 32) {
    lds_load16(aL0, aG0 + k0);
    lds_load16(aL1, aG1 + k0);
    lds_load16(bL0, bG0 + k0);
    if (NTILE == 128) lds_load16(bL1, bG1 + k0);
    __syncthreads();
    short8 af[MI], bfv[4];
#pragma unroll
    for (int i = 0; i < MI; i++)
      af[i] = *(const short8*)&As[(wr + i * 16 + fr) * 32 + fk];
#pragma unroll
    for (int j = 0; j < 4; j++)
      bfv[j] = *(const short8*)&Bs[(wc + j * 16 + fr) * 32 + fk];
#pragma unroll
    for (int i = 0; i < MI; i++)
#pragma unroll
      for (int j = 0; j < 4; j++)
        acc[i][j] = __builtin_amdgcn_mfma_f32_16x16x32_bf16(af[i], bfv[j], acc[i][j], 0, 0, 0);
    __syncthreads();
  }

  // epilogue: D[row][col], col = lane&15, row = (lane>>4)*4 + r  [m89-verified layout]
  const int cl = l & 15, rq = (l >> 4) * 4;
  const long cfBase = (long)imgA * p.sCfImg + (long)h * p.sCfH;
  const long cbBase = (long)imgA * p.sCbImg + (long)h * p.sCbH;
  const long chBase = (long)imgA * p.sChImg + (long)h * p.sChH;
#pragma unroll
  for (int j = 0; j < 4; j++) {
    const int col = n0 + wc + j * 16 + cl;
    if (col >= p.N) continue;
    const float bv = p.bias ? p.bias[col] : 0.f;
#pragma unroll
    for (int i = 0; i < MI; i++) {
#pragma unroll
      for (int r = 0; r < 4; r++) {
        const int row = m0 + wr + i * 16 + rq + r;
        float val = acc[i][j][r] * p.scale + bv;
        if (p.resid) val += p.resid[cfBase + (long)row * p.ldcf + col];
        if (p.Cf) p.Cf[cfBase + (long)row * p.ldcf + col] = val;
        if (p.Cb) p.Cb[cbBase + (long)row * p.ldcb + col] = __float2bfloat16(val);
        if (p.Ch) p.Ch[chBase + (long)row * p.ldch + col] = __float2half(val);
      }
    }
  }
}

// ---------------- elementwise / helper kernels ----------------
__global__ __launch_bounds__(256)
void cvt_f2b(const float* __restrict__ in, bf16* __restrict__ out, long n) {
  long i = (long)blockIdx.x * 256 + threadIdx.x;
  const long stride = (long)gridDim.x * 256;
  for (; i < n; i += stride) out[i] = __float2bfloat16(in[i]);
}

// fused per-layer weight conversion into rotating buffer (5 MB):
// [0:768K) wqkv stacked | [768K:1M) wm(col-permuted) | [1M:2M) w1 | [2M:2.5M) w2
// plus packed qkv bias (1536 floats)
__global__ __launch_bounds__(256)
void cvt_layer(const float* __restrict__ Wq, const float* __restrict__ Wk,
               const float* __restrict__ Wv, const float* __restrict__ Wm,
               const float* __restrict__ W1, const float* __restrict__ W2,
               const float* __restrict__ bq, const float* __restrict__ bk,
               const float* __restrict__ bv,
               int layer, bf16* __restrict__ out, float* __restrict__ bqkv) {
  const long i = (long)blockIdx.x * 256 + threadIdx.x;
  if (i >= 2621440L + 1536) return;
  if (i >= 2621440L) {
    const int j = (int)(i - 2621440L);
    float b;
    if (j < 512) b = bq[layer * 512 + j];
    else if (j < 1024) b = bk[layer * 512 + j - 512];
    else b = bv[layer * 512 + j - 1024];
    bqkv[j] = b;
    return;
  }
  float v;
  if (i < 262144) {
    v = Wq[(long)layer * 262144 + i];
  } else if (i < 524288) {
    v = Wk[(long)layer * 262144 + i - 262144];
  } else if (i < 786432) {
    v = Wv[(long)layer * 262144 + i - 524288];
  } else if (i < 1048576) {
    const long j = i - 786432;
    const int o = (int)(j >> 9), cp = (int)(j & 511);
    v = Wm[(long)layer * 262144 + o * 512 + (cp & 63) * 8 + (cp >> 6)];
  } else if (i < 2097152) {
    v = W1[(long)layer * 1048576 + i - 1048576];
  } else {
    v = W2[(long)layer * 524288 + i - 2097152];
  }
  out[i] = __float2bfloat16(v);
}

__global__ __launch_bounds__(256)
void init_x(const float* __restrict__ d0, const float* __restrict__ d1,
            float* __restrict__ Xf, bf16* __restrict__ Yb) {
  long i = (long)blockIdx.x * 256 + threadIdx.x;
  const long stride = (long)gridDim.x * 256;
  const long n = 8L * 1024 * 512;
  for (; i < n; i += stride) {
    const int d = (int)(i & 511);
    const long nn = i >> 9;  // img*1024 + row
    const int img = (int)(nn >> 10);
    const int row = (int)(nn & 1023);
    const int b = img >> 1, s = img & 1;
    const float v = (s ? d1 : d0)[((long)b * 1024 + row) * 512 + d];
    Xf[i] = v;
    Yb[(nn << 10) + d] = __float2bfloat16(v);
  }
}

// softmax over rows of 1024 fp16 logits, in-place rewrite as bf16 probs (wave per row)
__global__ __launch_bounds__(256)
void softmax_rows(__half* S) {
  const int w = threadIdx.x >> 6, l = threadIdx.x & 63;
  const long row = (long)blockIdx.x * 4 + w;
  __half* p = S + row * 1024;
  float xs[16];
  const __half2* hp = (const __half2*)(p + l * 16);
#pragma unroll
  for (int i = 0; i < 8; i++) {
    float2 f = __half22float2(hp[i]);
    xs[2 * i] = f.x; xs[2 * i + 1] = f.y;
  }
  float mx = xs[0];
#pragma unroll
  for (int i = 1; i < 16; i++) mx = fmaxf(mx, xs[i]);
#pragma unroll
  for (int o = 32; o >= 1; o >>= 1) mx = fmaxf(mx, __shfl_xor(mx, o));
  float s = 0.f;
#pragma unroll
  for (int i = 0; i < 16; i++) { xs[i] = __expf(xs[i] - mx); s += xs[i]; }
#pragma unroll
  for (int o = 32; o >= 1; o >>= 1) s += __shfl_xor(s, o);
  const float inv = 1.f / s;
  bf16* ob = (bf16*)p;
#pragma unroll
  for (int i = 0; i < 16; i++) ob[l * 16 + i] = __float2bfloat16(xs[i] * inv);
}

// transpose [8][1024][512-cols-of-ldi] (2-byte elems) -> [8][512][1024]
__global__ __launch_bounds__(256)
void transpose_2b(const unsigned short* __restrict__ in, int ldi,
                  unsigned short* __restrict__ out) {
  __shared__ unsigned short tile[64][65];
  const int img = blockIdx.z;
  const int m0 = blockIdx.y * 64, c0 = blockIdx.x * 64;
  const int col = threadIdx.x & 63, r0 = threadIdx.x >> 6;
  const unsigned short* ip = in + ((long)img * 1024 + m0) * ldi + c0;
#pragma unroll
  for (int i = 0; i < 16; i++) { int r = r0 + i * 4; tile[r][col] = ip[(long)r * ldi + col]; }
  __syncthreads();
  unsigned short* op = out + ((long)img * 512 + c0) * 1024 + m0;
#pragma unroll
  for (int i = 0; i < 16; i++) { int r = r0 + i * 4; op[(long)r * 1024 + col] = tile[col][r]; }
}

// instance-norm stats: column sums over n per (img, channel); stats pre-zeroed
__global__ __launch_bounds__(256)
void in_stats(const float* __restrict__ T1, float* __restrict__ stats) {
  const int img = blockIdx.z;
  const int c = blockIdx.x * 256 + threadIdx.x;
  const int nb = blockIdx.y;
  const float* p = T1 + ((long)img * 1024 + nb * 128) * 1024 + c;
  float s = 0.f, s2 = 0.f;
#pragma unroll 4
  for (int i = 0; i < 128; i++) { const float x = p[(long)i * 1024]; s += x; s2 += x * x; }
  atomicAdd(&stats[img * 2048 + c], s);
  atomicAdd(&stats[img * 2048 + 1024 + c], s2);
}

__global__ __launch_bounds__(256)
void in_apply(const float* __restrict__ T1, const float* __restrict__ stats,
              bf16* __restrict__ Z) {
  long i = (long)blockIdx.x * 256 + threadIdx.x;
  const long stride = (long)gridDim.x * 256;
  for (; i < 8L * 1024 * 1024; i += stride) {
    const int c = (int)(i & 1023);
    const int img = (int)(i >> 20);
    const float mean = stats[img * 2048 + c] * (1.f / 1024.f);
    const float var = fmaxf(stats[img * 2048 + 1024 + c] * (1.f / 1024.f) - mean * mean, 0.f);
    const float zz = (T1[i] - mean) * rsqrtf(var + 1e-5f);
    Z[i] = __float2bfloat16(fmaxf(zz, 0.f));
  }
}

__global__ __launch_bounds__(256)
void fill_bins(float* C, const float* alpha) {
  const int i = blockIdx.x * 256 + threadIdx.x;
  if (i >= 4 * 1025) return;
  const float a = *alpha;
  const int b = i / 1025, n = i - b * 1025;
  C[((long)b * 1025 + n) * 1025 + 1024] = a;
  C[((long)b * 1025 + 1024) * 1025 + n] = a;
}

__global__ __launch_bounds__(256)
void transpose_coup(const float* __restrict__ in, float* __restrict__ out) {
  __shared__ float tile[32][33];
  const int b = blockIdx.z;
  const int x0 = blockIdx.x * 32, y0 = blockIdx.y * 32;
  const int lx = threadIdx.x & 31, ly = threadIdx.x >> 5;  // ly 0..7
#pragma unroll
  for (int i = 0; i < 4; i++) {
    const int y = ly + i * 8;
    if (y0 + y < 1025 && x0 + lx < 1025)
      tile[y][lx] = in[((long)b * 1025 + y0 + y) * 1025 + x0 + lx];
  }
  __syncthreads();
#pragma unroll
  for (int i = 0; i < 4; i++) {
    const int y = ly + i * 8;
    if (x0 + y < 1025 && y0 + lx < 1025)
      out[((long)b * 1025 + x0 + y) * 1025 + y0 + lx] = tile[lx][y];
  }
}

// all 100 Sinkhorn iterations in ONE cooperative launch (grid.sync between halves).
// 256 blocks x 4 waves = 1024 waves; each wave owns 4-5 rows (L1-resident, 16-20KB).
__device__ __forceinline__ float wave_lse_row(const float* __restrict__ row,
                                              const float* __restrict__ add, int l) {
  float M = -3.0e38f, S = 0.f;
  for (int m = l; m < 1025; m += 64) {
    const float x = row[m] + add[m];
    const float Mn = fmaxf(M, x);
    S = S * __expf(M - Mn) + __expf(x - Mn);
    M = Mn;
  }
#pragma unroll
  for (int o = 32; o >= 1; o >>= 1) {
    const float Mo = __shfl_xor(M, o);
    const float So = __shfl_xor(S, o);
    const float Mn = fmaxf(M, Mo);
    S = S * __expf(M - Mn) + So * __expf(Mo - Mn);
    M = Mn;
  }
  return M + __logf(S);
}

__global__ __launch_bounds__(256)
void sinkhorn_coop(const float* __restrict__ C, const float* __restrict__ CT,
                   float* __restrict__ u, float* __restrict__ v,
                   float norm, float logN, int iters) {
  cg::grid_group grid = cg::this_grid();
  const int w = threadIdx.x >> 6, l = threadIdx.x & 63;
  const int wid = blockIdx.x * 4 + w;  // 0..1023
  {
    const int i = blockIdx.x * 256 + threadIdx.x;
    if (i < 4100) { u[i] = 0.f; v[i] = 0.f; }
  }
  grid.sync();
  for (int it = 0; it < iters; it++) {
    for (int gw = wid; gw < 4100; gw += 1024) {
      const int b = gw / 1025, n = gw - b * 1025;
      const float lse = wave_lse_row(C + ((long)b * 1025 + n) * 1025, v + b * 1025, l);
      if (l == 0) u[gw] = ((n == 1024) ? (logN + norm) : norm) - lse;
    }
    grid.sync();
    for (int gw = wid; gw < 4100; gw += 1024) {
      const int b = gw / 1025, n = gw - b * 1025;
      const float lse = wave_lse_row(CT + ((long)b * 1025 + n) * 1025, u + b * 1025, l);
      if (l == 0) v[gw] = ((n == 1024) ? (logN + norm) : norm) - lse;
    }
    grid.sync();
  }
}

__global__ __launch_bounds__(256)
void ot_final(float* __restrict__ C, const float* __restrict__ u,
              const float* __restrict__ v, float norm) {
  long i = (long)blockIdx.x * 256 + threadIdx.x;
  if (i >= 4L * 1025 * 1025) return;
  const int b = (int)(i / 1050625);
  const long r = i - (long)b * 1050625;
  const int n = (int)(r / 1025);
  const int m = (int)(r - (long)n * 1025);
  C[i] += u[b * 1025 + n] + v[b * 1025 + m] - norm;
}

// ---------------- host ----------------
extern "C" void kernel_launch(void* const* d_in, const int* in_sizes, int n_in,
                              void* d_out, int out_size, void* d_ws, size_t ws_size,
                              hipStream_t stream) {
  (void)in_sizes; (void)n_in; (void)out_size;
  const float* descs0 = (const float*)d_in[0];
  const float* descs1 = (const float*)d_in[1];
  const float* Wq = (const float*)d_in[2];
  const float* bq = (const float*)d_in[3];
  const float* Wk = (const float*)d_in[4];
  const float* bk = (const float*)d_in[5];
  const float* Wv = (const float*)d_in[6];
  const float* bvv = (const float*)d_in[7];
  const float* Wm = (const float*)d_in[8];
  const float* bm = (const float*)d_in[9];
  const float* W1 = (const float*)d_in[10];
  const float* b1 = (const float*)d_in[11];
  const float* W2 = (const float*)d_in[12];
  const float* b2 = (const float*)d_in[13];
  const float* Wf = (const float*)d_in[14];
  const float* bff = (const float*)d_in[15];
  const float* alpha = (const float*)d_in[16];

  char* ws = (char*)d_ws;
  size_t off = 0;
  auto alloc = [&](size_t bytes) -> void* {
    off = (off + 255) & ~(size_t)255;
    void* p = ws + off;
    off += bytes;
    return p;
  };

  // adaptive attention chunking: full scores buffer needs ~206 MB of ws
  const bool full = ws_size >= ((size_t)210 << 20);
  const int nch = full ? 1 : 4;
  const int chImgs = full ? 8 : 2;
  const size_t scrBytes = full ? ((size_t)chImgs * 8 * 1024 * 1024 * 2)  // 128 MB
                               : 50331648;                               // 48 MB

  bf16* wL = (bf16*)alloc(2621440L * 2);           // rotating per-layer weights (5 MB)
  float* bqkv = (float*)alloc(1536 * 4);
  bf16* WfB = (bf16*)alloc(512L * 512 * 2);
  float* Xf = (float*)alloc(8L * 1024 * 512 * 4);  // fp32 residual stream
  bf16* Yb = (bf16*)alloc(8L * 1024 * 1024 * 2);   // [img][n][1024]: 0:512 x, 512:1024 msg
  bf16* QKVb = (bf16*)alloc(8L * 1024 * 1536 * 2); // [token][1536] q|k|v
  bf16* vchan = (bf16*)alloc(8L * 1024 * 512 * 2); // [img][512ch][1024tok]
  bf16* Ob = (bf16*)alloc(8L * 1024 * 512 * 2);    // attn out [token][512]
  char* SCR = (char*)alloc(scrBytes);              // scores / T1+Zb / coupT+mproj
  float* stats = (float*)alloc(8L * 2048 * 4);
  float* u = (float*)alloc(4L * 1025 * 4);
  float* v = (float*)alloc(4L * 1025 * 4);

  bf16* wqkv = wL;                 // [1536][512]
  bf16* wm = wL + 786432;
  bf16* w1 = wL + 1048576;
  bf16* w2 = wL + 2097152;
  __half* scoresH = (__half*)SCR;  // chunk: chImgs*8*1024*1024 fp16
  bf16* probsB = (bf16*)SCR;
  float* T1 = (float*)SCR;                 // 32 MB
  bf16* Zb = (bf16*)(SCR + 33554432);      // 16 MB
  float* coupT = (float*)SCR;              // 16.8 MB (post-layers)
  bf16* mproj = (bf16*)(SCR + 33554432);   // 8 MB (post-layers)
  float* coup = (float*)d_out;

  cvt_f2b<<<512, 256, 0, stream>>>(Wf, WfB, 512L * 512);
  init_x<<<4096, 256, 0, stream>>>(descs0, descs1, Xf, Yb);

  auto gemm = [&](int ntile, const bf16* A, const bf16* B, int M, int N, int K,
                  int lda, int ldb, long sAimg, long sAh, long sBimg, long sBh,
                  int Z, int ZH, int cross, float scale, const float* bias,
                  float* Cf, int ldcf, long sCfImg, long sCfH,
                  bf16* Cb, int ldcb, long sCbImg, long sCbH,
                  __half* Ch, int ldch, long sChImg, long sChH,
                  const float* resid) {
    GemmP p;
    p.A = A; p.B = B; p.M = M; p.N = N; p.K = K; p.lda = lda; p.ldb = ldb;
    p.sAimg = sAimg; p.sAh = sAh; p.sBimg = sBimg; p.sBh = sBh;
    p.ZH = ZH; p.cross = cross; p.scale = scale; p.bias = bias;
    p.Cf = Cf; p.ldcf = ldcf; p.sCfImg = sCfImg; p.sCfH = sCfH;
    p.Cb = Cb; p.ldcb = ldcb; p.sCbImg = sCbImg; p.sCbH = sCbH;
    p.Ch = Ch; p.ldch = ldch; p.sChImg = sChImg; p.sChH = sChH;
    p.resid = resid;
    dim3 g((unsigned)((N + ntile - 1) / ntile), (unsigned)((M + 127) / 128), (unsigned)Z);
    if (ntile == 128) gemm_bt<128><<<g, 256, 0, stream>>>(p);
    else gemm_bt<64><<<g, 256, 0, stream>>>(p);
  };

  for (int i = 0; i < 12; i++) {
    const int cross = i & 1;  // NAMES = self,cross,self,...
    cvt_layer<<<10247, 256, 0, stream>>>(Wq, Wk, Wv, Wm, W1, W2, bq, bk, bvv, i, wL, bqkv);

    // fused QKV: [8192,1536] = Yb[:, :512] x Wqkv^T
    gemm(128, Yb, wqkv, 8192, 1536, 512, 1024, 512, 0, 0, 0, 0, 1, 1, 0, 1.f, bqkv,
         nullptr, 0, 0, 0, QKVb, 1536, 0, 0, nullptr, 0, 0, 0, nullptr);
    // v channels -> channel-major
    transpose_2b<<<dim3(8, 16, 8), 256, 0, stream>>>((const unsigned short*)(QKVb + 1024),
                                                     1536, (unsigned short*)vchan);
    for (int c = 0; c < nch; c++) {
      const long tokOfs = (long)c * chImgs * 1024 * 1536;
      // scores[limg][h][n][m] = q.k^T / 8  (fp16)
      gemm(128, QKVb + tokOfs, QKVb + tokOfs + 512, 1024, 1024, 64, 1536, 1536,
           1572864, 64, 1572864, 64, chImgs * 8, 8, cross,
           0.125f, nullptr,
           nullptr, 0, 0, 0, nullptr, 0, 0, 0,
           scoresH, 1024, 8L * 1048576, 1048576, nullptr);
      softmax_rows<<<chImgs * 2048, 256, 0, stream>>>(scoresH);
      // O[limg][n][h*64+dh] = probs x V  (NTILE=64: no wasted MFMA on N=64)
      gemm(64, probsB, vchan + (long)c * chImgs * 524288, 1024, 64, 1024, 1024, 1024,
           8L * 1048576, 1048576, 524288, 65536, chImgs * 8, 8, cross,
           1.f, nullptr,
           nullptr, 0, 0, 0, Ob + (long)c * chImgs * 524288, 512, 524288, 64,
           nullptr, 0, 0, 0, nullptr);
    }
    // msg -> Yb[:, 512:1024]  (wm pre-permuted for head-merge order)
    gemm(128, Ob, wm, 8192, 512, 512, 512, 512, 0, 0, 0, 0, 1, 1, 0, 1.f, bm + i * 512,
         nullptr, 0, 0, 0, Yb + 512, 1024, 0, 0, nullptr, 0, 0, 0, nullptr);
    // T1 = W1 x [x; msg] + b1 (fp32)
    gemm(128, Yb, w1, 8192, 1024, 1024, 1024, 1024, 0, 0, 0, 0, 1, 1, 0, 1.f, b1 + i * 1024,
         T1, 1024, 0, 0, nullptr, 0, 0, 0, nullptr, 0, 0, 0, nullptr);
    hipMemsetAsync(stats, 0, 8L * 2048 * 4, stream);
    in_stats<<<dim3(4, 8, 8), 256, 0, stream>>>(T1, stats);
    in_apply<<<8192, 256, 0, stream>>>(T1, stats, Zb);
    // x += W2 z + b2 : fp32 residual into Xf, bf16 mirror into Yb[:, :512]
    gemm(128, Zb, w2, 8192, 512, 1024, 1024, 1024, 0, 0, 0, 0, 1, 1, 0, 1.f, b2 + i * 512,
         Xf, 512, 0, 0, Yb, 1024, 0, 0, nullptr, 0, 0, 0, Xf);
  }

  // final projection + score matrix into d_out
  gemm(128, Yb, WfB, 8192, 512, 512, 1024, 512, 0, 0, 0, 0, 1, 1, 0, 1.f, bff,
       nullptr, 0, 0, 0, mproj, 512, 0, 0, nullptr, 0, 0, 0, nullptr);
  gemm(128, mproj, mproj + 524288, 1024, 1024, 512, 512, 512,
       1048576, 0, 1048576, 0, 4, 1, 0,
       0.044194173824159216f, nullptr,
       coup, 1025, 1050625, 0, nullptr, 0, 0, 0, nullptr, 0, 0, 0, nullptr);
  fill_bins<<<17, 256, 0, stream>>>(coup, alpha);
  transpose_coup<<<dim3(33, 33, 4), 256, 0, stream>>>(coup, coupT);

  const float NORM = -logf(2048.f);
  const float LOGN = logf(1024.f);
  int iters = 100;
  void* args[] = {(void*)&coup, (void*)&coupT, (void*)&u, (void*)&v,
                  (void*)&NORM, (void*)&LOGN, (void*)&iters};
  hipLaunchCooperativeKernel((void*)sinkhorn_coop, dim3(256), dim3(256), args, 0, stream);
  ot_final<<<16417, 256, 0, stream>>>(coup, u, v, NORM);
}

// Round 4
// 8051.052 us; speedup vs baseline: 1.7323x; 1.7323x over previous
//
#include <hip/hip_runtime.h>
#include <hip/hip_bf16.h>
#include <hip/hip_fp16.h>
#include <cmath>

using bf16 = __hip_bfloat16;
typedef __attribute__((ext_vector_type(8))) short short8;
typedef __attribute__((ext_vector_type(4))) float floatx4;

__device__ __forceinline__ void lds_load16(void* lds, const void* g) {
  __builtin_amdgcn_global_load_lds(
      (const __attribute__((address_space(1))) void*)g,
      (__attribute__((address_space(3))) void*)lds, 16, 0, 0);
}

// ---------------- generic BT GEMM: C[M][N] = scale*(A[M][K] x B[N][K]^T) + bias ----------
struct GemmP {
  const bf16* A; const bf16* B;
  int M, N, K, lda, ldb;
  long sAimg, sAh, sBimg, sBh;
  int ZH, cross;
  float scale;
  const float* bias;
  float* Cf; int ldcf; long sCfImg, sCfH;
  bf16* Cb; int ldcb; long sCbImg, sCbH;
  __half* Ch; int ldch; long sChImg, sChH;
  const float* resid;  // fp32, same indexing as Cf
};

template <int NTILE>  // 128: 4 waves x (64x64); 64: 4 waves x (32x64)
__global__ __launch_bounds__(256, 2)
void gemm_bt(GemmP p) {
  __shared__ __align__(16) bf16 As[128 * 32];
  __shared__ __align__(16) bf16 Bs[NTILE * 32];
  constexpr int MI = (NTILE == 128) ? 4 : 2;
  const int z = blockIdx.z;
  const int imgA = z / p.ZH;
  const int h = z - imgA * p.ZH;
  const int imgB = imgA ^ p.cross;
  const bf16* Ab = p.A + (long)imgA * p.sAimg + (long)h * p.sAh;
  const bf16* Bb = p.B + (long)imgB * p.sBimg + (long)h * p.sBh;
  const int m0 = blockIdx.y * 128, n0 = blockIdx.x * NTILE;
  const int t = threadIdx.x, w = t >> 6, l = t & 63;
  const int lr = l >> 2, lk = (l & 3) * 8;   // staging: row-in-chunk, k-elem offset
  const int fr = l & 15, fk = (l >> 4) * 8;  // fragment: row-in-16tile, k offset

  const bf16* aG0 = Ab + (long)(m0 + w * 16 + lr) * p.lda + lk;
  const bf16* aG1 = aG0 + (long)64 * p.lda;
  const bf16* bG0 = Bb + (long)(n0 + w * 16 + lr) * p.ldb + lk;
  const bf16* bG1 = bG0 + (long)64 * p.ldb;
  bf16* aL0 = &As[w * 16 * 32];
  bf16* aL1 = &As[(w + 4) * 16 * 32];
  bf16* bL0 = &Bs[w * 16 * 32];
  bf16* bL1 = &Bs[(w + 4) * 16 * 32];
  const int wr = (NTILE == 128) ? (w >> 1) * 64 : w * 32;
  const int wc = (NTILE == 128) ? (w & 1) * 64 : 0;

  floatx4 zero4 = {0.f, 0.f, 0.f, 0.f};
  floatx4 acc[MI][4];
#pragma unroll
  for (int i = 0; i < MI; i++)
#pragma unroll
    for (int j = 0; j < 4; j++) acc[i][j] = zero4;

  for (int k0 = 0; k0 < p.K; k0 += 32) {
    lds_load16(aL0, aG0 + k0);
    lds_load16(aL1, aG1 + k0);
    lds_load16(bL0, bG0 + k0);
    if (NTILE == 128) lds_load16(bL1, bG1 + k0);
    __syncthreads();
    short8 af[MI], bfv[4];
#pragma unroll
    for (int i = 0; i < MI; i++)
      af[i] = *(const short8*)&As[(wr + i * 16 + fr) * 32 + fk];
#pragma unroll
    for (int j = 0; j < 4; j++)
      bfv[j] = *(const short8*)&Bs[(wc + j * 16 + fr) * 32 + fk];
#pragma unroll
    for (int i = 0; i < MI; i++)
#pragma unroll
      for (int j = 0; j < 4; j++)
        acc[i][j] = __builtin_amdgcn_mfma_f32_16x16x32_bf16(af[i], bfv[j], acc[i][j], 0, 0, 0);
    __syncthreads();
  }

  // epilogue: D[row][col], col = lane&15, row = (lane>>4)*4 + r  [m89-verified layout]
  const int cl = l & 15, rq = (l >> 4) * 4;
  const long cfBase = (long)imgA * p.sCfImg + (long)h * p.sCfH;
  const long cbBase = (long)imgA * p.sCbImg + (long)h * p.sCbH;
  const long chBase = (long)imgA * p.sChImg + (long)h * p.sChH;
#pragma unroll
  for (int j = 0; j < 4; j++) {
    const int col = n0 + wc + j * 16 + cl;
    if (col >= p.N) continue;
    const float bv = p.bias ? p.bias[col] : 0.f;
#pragma unroll
    for (int i = 0; i < MI; i++) {
#pragma unroll
      for (int r = 0; r < 4; r++) {
        const int row = m0 + wr + i * 16 + rq + r;
        float val = acc[i][j][r] * p.scale + bv;
        if (p.resid) val += p.resid[cfBase + (long)row * p.ldcf + col];
        if (p.Cf) p.Cf[cfBase + (long)row * p.ldcf + col] = val;
        if (p.Cb) p.Cb[cbBase + (long)row * p.ldcb + col] = __float2bfloat16(val);
        if (p.Ch) p.Ch[chBase + (long)row * p.ldch + col] = __float2half(val);
      }
    }
  }
}

// ---------------- elementwise / helper kernels ----------------
__global__ __launch_bounds__(256)
void cvt_f2b(const float* __restrict__ in, bf16* __restrict__ out, long n) {
  long i = (long)blockIdx.x * 256 + threadIdx.x;
  const long stride = (long)gridDim.x * 256;
  for (; i < n; i += stride) out[i] = __float2bfloat16(in[i]);
}

// fused per-layer weight conversion into rotating buffer (5 MB):
// [0:768K) wqkv stacked | [768K:1M) wm(col-permuted) | [1M:2M) w1 | [2M:2.5M) w2
// plus packed qkv bias (1536 floats)
__global__ __launch_bounds__(256)
void cvt_layer(const float* __restrict__ Wq, const float* __restrict__ Wk,
               const float* __restrict__ Wv, const float* __restrict__ Wm,
               const float* __restrict__ W1, const float* __restrict__ W2,
               const float* __restrict__ bq, const float* __restrict__ bk,
               const float* __restrict__ bv,
               int layer, bf16* __restrict__ out, float* __restrict__ bqkv) {
  const long i = (long)blockIdx.x * 256 + threadIdx.x;
  if (i >= 2621440L + 1536) return;
  if (i >= 2621440L) {
    const int j = (int)(i - 2621440L);
    float b;
    if (j < 512) b = bq[layer * 512 + j];
    else if (j < 1024) b = bk[layer * 512 + j - 512];
    else b = bv[layer * 512 + j - 1024];
    bqkv[j] = b;
    return;
  }
  float v;
  if (i < 262144) {
    v = Wq[(long)layer * 262144 + i];
  } else if (i < 524288) {
    v = Wk[(long)layer * 262144 + i - 262144];
  } else if (i < 786432) {
    v = Wv[(long)layer * 262144 + i - 524288];
  } else if (i < 1048576) {
    const long j = i - 786432;
    const int o = (int)(j >> 9), cp = (int)(j & 511);
    v = Wm[(long)layer * 262144 + o * 512 + (cp & 63) * 8 + (cp >> 6)];
  } else if (i < 2097152) {
    v = W1[(long)layer * 1048576 + i - 1048576];
  } else {
    v = W2[(long)layer * 524288 + i - 2097152];
  }
  out[i] = __float2bfloat16(v);
}

__global__ __launch_bounds__(256)
void init_x(const float* __restrict__ d0, const float* __restrict__ d1,
            float* __restrict__ Xf, bf16* __restrict__ Yb) {
  long i = (long)blockIdx.x * 256 + threadIdx.x;
  const long stride = (long)gridDim.x * 256;
  const long n = 8L * 1024 * 512;
  for (; i < n; i += stride) {
    const int d = (int)(i & 511);
    const long nn = i >> 9;  // img*1024 + row
    const int img = (int)(nn >> 10);
    const int row = (int)(nn & 1023);
    const int b = img >> 1, s = img & 1;
    const float v = (s ? d1 : d0)[((long)b * 1024 + row) * 512 + d];
    Xf[i] = v;
    Yb[(nn << 10) + d] = __float2bfloat16(v);
  }
}

// softmax over rows of 1024 fp16 logits, in-place rewrite as bf16 probs (wave per row)
__global__ __launch_bounds__(256)
void softmax_rows(__half* S) {
  const int w = threadIdx.x >> 6, l = threadIdx.x & 63;
  const long row = (long)blockIdx.x * 4 + w;
  __half* p = S + row * 1024;
  float xs[16];
  const __half2* hp = (const __half2*)(p + l * 16);
#pragma unroll
  for (int i = 0; i < 8; i++) {
    float2 f = __half22float2(hp[i]);
    xs[2 * i] = f.x; xs[2 * i + 1] = f.y;
  }
  float mx = xs[0];
#pragma unroll
  for (int i = 1; i < 16; i++) mx = fmaxf(mx, xs[i]);
#pragma unroll
  for (int o = 32; o >= 1; o >>= 1) mx = fmaxf(mx, __shfl_xor(mx, o));
  float s = 0.f;
#pragma unroll
  for (int i = 0; i < 16; i++) { xs[i] = __expf(xs[i] - mx); s += xs[i]; }
#pragma unroll
  for (int o = 32; o >= 1; o >>= 1) s += __shfl_xor(s, o);
  const float inv = 1.f / s;
  bf16* ob = (bf16*)p;
#pragma unroll
  for (int i = 0; i < 16; i++) ob[l * 16 + i] = __float2bfloat16(xs[i] * inv);
}

// transpose [8][1024][512-cols-of-ldi] (2-byte elems) -> [8][512][1024]
__global__ __launch_bounds__(256)
void transpose_2b(const unsigned short* __restrict__ in, int ldi,
                  unsigned short* __restrict__ out) {
  __shared__ unsigned short tile[64][65];
  const int img = blockIdx.z;
  const int m0 = blockIdx.y * 64, c0 = blockIdx.x * 64;
  const int col = threadIdx.x & 63, r0 = threadIdx.x >> 6;
  const unsigned short* ip = in + ((long)img * 1024 + m0) * ldi + c0;
#pragma unroll
  for (int i = 0; i < 16; i++) { int r = r0 + i * 4; tile[r][col] = ip[(long)r * ldi + col]; }
  __syncthreads();
  unsigned short* op = out + ((long)img * 512 + c0) * 1024 + m0;
#pragma unroll
  for (int i = 0; i < 16; i++) { int r = r0 + i * 4; op[(long)r * 1024 + col] = tile[col][r]; }
}

// instance-norm stats: column sums over n per (img, channel); stats pre-zeroed
__global__ __launch_bounds__(256)
void in_stats(const float* __restrict__ T1, float* __restrict__ stats) {
  const int img = blockIdx.z;
  const int c = blockIdx.x * 256 + threadIdx.x;
  const int nb = blockIdx.y;
  const float* p = T1 + ((long)img * 1024 + nb * 128) * 1024 + c;
  float s = 0.f, s2 = 0.f;
#pragma unroll 4
  for (int i = 0; i < 128; i++) { const float x = p[(long)i * 1024]; s += x; s2 += x * x; }
  atomicAdd(&stats[img * 2048 + c], s);
  atomicAdd(&stats[img * 2048 + 1024 + c], s2);
}

__global__ __launch_bounds__(256)
void in_apply(const float* __restrict__ T1, const float* __restrict__ stats,
              bf16* __restrict__ Z) {
  long i = (long)blockIdx.x * 256 + threadIdx.x;
  const long stride = (long)gridDim.x * 256;
  for (; i < 8L * 1024 * 1024; i += stride) {
    const int c = (int)(i & 1023);
    const int img = (int)(i >> 20);
    const float mean = stats[img * 2048 + c] * (1.f / 1024.f);
    const float var = fmaxf(stats[img * 2048 + 1024 + c] * (1.f / 1024.f) - mean * mean, 0.f);
    const float zz = (T1[i] - mean) * rsqrtf(var + 1e-5f);
    Z[i] = __float2bfloat16(fmaxf(zz, 0.f));
  }
}

__global__ __launch_bounds__(256)
void fill_bins(float* C, const float* alpha) {
  const int i = blockIdx.x * 256 + threadIdx.x;
  if (i >= 4 * 1025) return;
  const float a = *alpha;
  const int b = i / 1025, n = i - b * 1025;
  C[((long)b * 1025 + n) * 1025 + 1024] = a;
  C[((long)b * 1025 + 1024) * 1025 + n] = a;
}

// fp32 coupling -> fp16 straight copy + fp16 transpose (for L2-resident sinkhorn)
__global__ __launch_bounds__(256)
void coup_to_fp16(const float* __restrict__ in, __half* __restrict__ outN,
                  __half* __restrict__ outT) {
  __shared__ float tile[32][33];
  const int b = blockIdx.z;
  const int x0 = blockIdx.x * 32, y0 = blockIdx.y * 32;
  const int lx = threadIdx.x & 31, ly = threadIdx.x >> 5;  // ly 0..7
#pragma unroll
  for (int i = 0; i < 4; i++) {
    const int y = ly + i * 8;
    if (y0 + y < 1025 && x0 + lx < 1025) {
      const float vv = in[((long)b * 1025 + y0 + y) * 1025 + x0 + lx];
      tile[y][lx] = vv;
      outN[((long)b * 1025 + y0 + y) * 1025 + x0 + lx] = __float2half(vv);
    }
  }
  __syncthreads();
#pragma unroll
  for (int i = 0; i < 4; i++) {
    const int y = ly + i * 8;
    if (x0 + y < 1025 && y0 + lx < 1025)
      outT[((long)b * 1025 + x0 + y) * 1025 + y0 + lx] = __float2half(tile[lx][y]);
  }
}

// -------- persistent Sinkhorn: 64 blocks x 1024 threads, custom lightweight barrier ------
// grid.sync() costs ~51us; this barrier (64 LLC atomics + spin) should be ~1-2us.
// C/CT are fp16 and read with PLAIN (cached) loads — read-only, so per-XCD L2 keeps each
// block's fixed 256KB row-slice resident across all 100 iterations. Only u/v (16KB) cross
// XCDs, via AGENT-scope atomics staged through LDS.
#define SK_BLOCKS 64

__global__ __launch_bounds__(1024)
void sinkhorn_pers(const __half* __restrict__ C, const __half* __restrict__ CT,
                   float* __restrict__ u, float* __restrict__ v,
                   unsigned int* __restrict__ ctr,
                   float norm, float logN, int iters) {
  __shared__ float sv[4100];
  const int t = threadIdx.x;
  const int w = t >> 6, l = t & 63;
  const int wid = blockIdx.x * 16 + w;  // 0..1023
  unsigned int barTarget = 0;

  for (int it = 0; it < iters; it++) {
#pragma unroll
    for (int half = 0; half < 2; half++) {
      const float* src = half ? u : v;
      float* dst = half ? v : u;
      const __half* mat = half ? CT : C;
      // stage src vector (all 4 batches) into LDS via device-scope loads
      for (int i = t; i < 4100; i += 1024)
        sv[i] = __hip_atomic_load(&src[i], __ATOMIC_RELAXED, __HIP_MEMORY_SCOPE_AGENT);
      __syncthreads();
      // each wave: ~4 rows (fixed mapping -> L2-resident slices)
      for (int gw = wid; gw < 4100; gw += 1024) {
        const int b = gw / 1025, n = gw - b * 1025;
        const __half* row = mat + ((long)b * 1025 + n) * 1025;
        const float* vv = &sv[b * 1025];
        float M = -3.0e38f, S = 0.f;
        for (int m = l; m < 1025; m += 64) {
          const float x = __half2float(row[m]) + vv[m];
          const float Mn = fmaxf(M, x);
          S = S * __expf(M - Mn) + __expf(x - Mn);
          M = Mn;
        }
#pragma unroll
        for (int o = 32; o >= 1; o >>= 1) {
          const float Mo = __shfl_xor(M, o);
          const float So = __shfl_xor(S, o);
          const float Mn = fmaxf(M, Mo);
          S = S * __expf(M - Mn) + So * __expf(Mo - Mn);
          M = Mn;
        }
        if (l == 0) {
          const float val = ((n == 1024) ? (logN + norm) : norm) - (M + __logf(S));
          __hip_atomic_store(&dst[gw], val, __ATOMIC_RELAXED, __HIP_MEMORY_SCOPE_AGENT);
        }
      }
      // ---- lightweight device barrier ----
      __syncthreads();  // drains this block's AGENT stores (vmcnt) & protects sv reuse
      barTarget += SK_BLOCKS;
      if (t == 0) {
        __hip_atomic_fetch_add(ctr, 1u, __ATOMIC_RELEASE, __HIP_MEMORY_SCOPE_AGENT);
        while (__hip_atomic_load(ctr, __ATOMIC_ACQUIRE, __HIP_MEMORY_SCOPE_AGENT) < barTarget)
          __builtin_amdgcn_s_sleep(1);
      }
      __syncthreads();
    }
  }
}

__global__ __launch_bounds__(256)
void ot_final(float* __restrict__ C, const float* __restrict__ u,
              const float* __restrict__ v, float norm) {
  long i = (long)blockIdx.x * 256 + threadIdx.x;
  if (i >= 4L * 1025 * 1025) return;
  const int b = (int)(i / 1050625);
  const long r = i - (long)b * 1050625;
  const int n = (int)(r / 1025);
  const int m = (int)(r - (long)n * 1025);
  C[i] += u[b * 1025 + n] + v[b * 1025 + m] - norm;
}

// ---------------- host ----------------
extern "C" void kernel_launch(void* const* d_in, const int* in_sizes, int n_in,
                              void* d_out, int out_size, void* d_ws, size_t ws_size,
                              hipStream_t stream) {
  (void)in_sizes; (void)n_in; (void)out_size;
  const float* descs0 = (const float*)d_in[0];
  const float* descs1 = (const float*)d_in[1];
  const float* Wq = (const float*)d_in[2];
  const float* bq = (const float*)d_in[3];
  const float* Wk = (const float*)d_in[4];
  const float* bk = (const float*)d_in[5];
  const float* Wv = (const float*)d_in[6];
  const float* bvv = (const float*)d_in[7];
  const float* Wm = (const float*)d_in[8];
  const float* bm = (const float*)d_in[9];
  const float* W1 = (const float*)d_in[10];
  const float* b1 = (const float*)d_in[11];
  const float* W2 = (const float*)d_in[12];
  const float* b2 = (const float*)d_in[13];
  const float* Wf = (const float*)d_in[14];
  const float* bff = (const float*)d_in[15];
  const float* alpha = (const float*)d_in[16];

  char* ws = (char*)d_ws;
  size_t off = 0;
  auto alloc = [&](size_t bytes) -> void* {
    off = (off + 255) & ~(size_t)255;
    void* p = ws + off;
    off += bytes;
    return p;
  };

  // adaptive attention chunking: full scores buffer needs ~206 MB of ws
  const bool full = ws_size >= ((size_t)210 << 20);
  const int nch = full ? 1 : 4;
  const int chImgs = full ? 8 : 2;
  const size_t scrBytes = full ? ((size_t)chImgs * 8 * 1024 * 1024 * 2)  // 128 MB
                               : 50331648;                               // 48 MB

  bf16* wL = (bf16*)alloc(2621440L * 2);           // rotating per-layer weights (5 MB)
  float* bqkv = (float*)alloc(1536 * 4);
  bf16* WfB = (bf16*)alloc(512L * 512 * 2);
  float* Xf = (float*)alloc(8L * 1024 * 512 * 4);  // fp32 residual stream
  bf16* Yb = (bf16*)alloc(8L * 1024 * 1024 * 2);   // [img][n][1024]: 0:512 x, 512:1024 msg
  bf16* QKVb = (bf16*)alloc(8L * 1024 * 1536 * 2); // [token][1536] q|k|v
  bf16* vchan = (bf16*)alloc(8L * 1024 * 512 * 2); // [img][512ch][1024tok]
  bf16* Ob = (bf16*)alloc(8L * 1024 * 512 * 2);    // attn out [token][512]
  char* SCR = (char*)alloc(scrBytes);              // scores / T1+Zb / Ch+CTh+mproj
  float* stats = (float*)alloc(8L * 2048 * 4);
  float* u = (float*)alloc(4L * 1025 * 4);
  float* v = (float*)alloc(4L * 1025 * 4);
  unsigned int* ctr = (unsigned int*)alloc(256);

  bf16* wqkv = wL;                 // [1536][512]
  bf16* wm = wL + 786432;
  bf16* w1 = wL + 1048576;
  bf16* w2 = wL + 2097152;
  __half* scoresH = (__half*)SCR;  // chunk: chImgs*8*1024*1024 fp16
  bf16* probsB = (bf16*)SCR;
  float* T1 = (float*)SCR;                 // 32 MB
  bf16* Zb = (bf16*)(SCR + 33554432);      // 16 MB
  __half* Ch = (__half*)SCR;               // 8.4 MB fp16 couplings (post-layers)
  __half* CTh = (__half*)(SCR + 8405248);  // 8.4 MB fp16 transposed
  bf16* mproj = (bf16*)(SCR + 33554432);   // 8 MB (post-layers)
  float* coup = (float*)d_out;

  cvt_f2b<<<512, 256, 0, stream>>>(Wf, WfB, 512L * 512);
  init_x<<<4096, 256, 0, stream>>>(descs0, descs1, Xf, Yb);

  auto gemm = [&](int ntile, const bf16* A, const bf16* B, int M, int N, int K,
                  int lda, int ldb, long sAimg, long sAh, long sBimg, long sBh,
                  int Z, int ZH, int cross, float scale, const float* bias,
                  float* Cf, int ldcf, long sCfImg, long sCfH,
                  bf16* Cb, int ldcb, long sCbImg, long sCbH,
                  __half* Ch_, int ldch, long sChImg, long sChH,
                  const float* resid) {
    GemmP p;
    p.A = A; p.B = B; p.M = M; p.N = N; p.K = K; p.lda = lda; p.ldb = ldb;
    p.sAimg = sAimg; p.sAh = sAh; p.sBimg = sBimg; p.sBh = sBh;
    p.ZH = ZH; p.cross = cross; p.scale = scale; p.bias = bias;
    p.Cf = Cf; p.ldcf = ldcf; p.sCfImg = sCfImg; p.sCfH = sCfH;
    p.Cb = Cb; p.ldcb = ldcb; p.sCbImg = sCbImg; p.sCbH = sCbH;
    p.Ch = Ch_; p.ldch = ldch; p.sChImg = sChImg; p.sChH = sChH;
    p.resid = resid;
    dim3 g((unsigned)((N + ntile - 1) / ntile), (unsigned)((M + 127) / 128), (unsigned)Z);
    if (ntile == 128) gemm_bt<128><<<g, 256, 0, stream>>>(p);
    else gemm_bt<64><<<g, 256, 0, stream>>>(p);
  };

  for (int i = 0; i < 12; i++) {
    const int cross = i & 1;  // NAMES = self,cross,self,...
    cvt_layer<<<10247, 256, 0, stream>>>(Wq, Wk, Wv, Wm, W1, W2, bq, bk, bvv, i, wL, bqkv);

    // fused QKV: [8192,1536] = Yb[:, :512] x Wqkv^T
    gemm(128, Yb, wqkv, 8192, 1536, 512, 1024, 512, 0, 0, 0, 0, 1, 1, 0, 1.f, bqkv,
         nullptr, 0, 0, 0, QKVb, 1536, 0, 0, nullptr, 0, 0, 0, nullptr);
    // v channels -> channel-major
    transpose_2b<<<dim3(8, 16, 8), 256, 0, stream>>>((const unsigned short*)(QKVb + 1024),
                                                     1536, (unsigned short*)vchan);
    for (int c = 0; c < nch; c++) {
      const long tokOfs = (long)c * chImgs * 1024 * 1536;
      // scores[limg][h][n][m] = q.k^T / 8  (fp16)
      gemm(128, QKVb + tokOfs, QKVb + tokOfs + 512, 1024, 1024, 64, 1536, 1536,
           1572864, 64, 1572864, 64, chImgs * 8, 8, cross,
           0.125f, nullptr,
           nullptr, 0, 0, 0, nullptr, 0, 0, 0,
           scoresH, 1024, 8L * 1048576, 1048576, nullptr);
      softmax_rows<<<chImgs * 2048, 256, 0, stream>>>(scoresH);
      // O[limg][n][h*64+dh] = probs x V  (NTILE=64: no wasted MFMA on N=64)
      gemm(64, probsB, vchan + (long)c * chImgs * 524288, 1024, 64, 1024, 1024, 1024,
           8L * 1048576, 1048576, 524288, 65536, chImgs * 8, 8, cross,
           1.f, nullptr,
           nullptr, 0, 0, 0, Ob + (long)c * chImgs * 524288, 512, 524288, 64,
           nullptr, 0, 0, 0, nullptr);
    }
    // msg -> Yb[:, 512:1024]  (wm pre-permuted for head-merge order)
    gemm(128, Ob, wm, 8192, 512, 512, 512, 512, 0, 0, 0, 0, 1, 1, 0, 1.f, bm + i * 512,
         nullptr, 0, 0, 0, Yb + 512, 1024, 0, 0, nullptr, 0, 0, 0, nullptr);
    // T1 = W1 x [x; msg] + b1 (fp32)
    gemm(128, Yb, w1, 8192, 1024, 1024, 1024, 1024, 0, 0, 0, 0, 1, 1, 0, 1.f, b1 + i * 1024,
         T1, 1024, 0, 0, nullptr, 0, 0, 0, nullptr, 0, 0, 0, nullptr);
    hipMemsetAsync(stats, 0, 8L * 2048 * 4, stream);
    in_stats<<<dim3(4, 8, 8), 256, 0, stream>>>(T1, stats);
    in_apply<<<8192, 256, 0, stream>>>(T1, stats, Zb);
    // x += W2 z + b2 : fp32 residual into Xf, bf16 mirror into Yb[:, :512]
    gemm(128, Zb, w2, 8192, 512, 1024, 1024, 1024, 0, 0, 0, 0, 1, 1, 0, 1.f, b2 + i * 512,
         Xf, 512, 0, 0, Yb, 1024, 0, 0, nullptr, 0, 0, 0, Xf);
  }

  // final projection + score matrix into d_out
  gemm(128, Yb, WfB, 8192, 512, 512, 1024, 512, 0, 0, 0, 0, 1, 1, 0, 1.f, bff,
       nullptr, 0, 0, 0, mproj, 512, 0, 0, nullptr, 0, 0, 0, nullptr);
  gemm(128, mproj, mproj + 524288, 1024, 1024, 512, 512, 512,
       1048576, 0, 1048576, 0, 4, 1, 0,
       0.044194173824159216f, nullptr,
       coup, 1025, 1050625, 0, nullptr, 0, 0, 0, nullptr, 0, 0, 0, nullptr);
  fill_bins<<<17, 256, 0, stream>>>(coup, alpha);
  coup_to_fp16<<<dim3(33, 33, 4), 256, 0, stream>>>(coup, Ch, CTh);

  hipMemsetAsync(u, 0, 4L * 1025 * 4, stream);
  hipMemsetAsync(v, 0, 4L * 1025 * 4, stream);
  hipMemsetAsync(ctr, 0, 256, stream);
  const float NORM = -logf(2048.f);
  const float LOGN = logf(1024.f);
  int iters = 100;
  void* args[] = {(void*)&Ch, (void*)&CTh, (void*)&u, (void*)&v, (void*)&ctr,
                  (void*)&NORM, (void*)&LOGN, (void*)&iters};
  hipLaunchCooperativeKernel((void*)sinkhorn_pers, dim3(SK_BLOCKS), dim3(1024), args, 0, stream);
  ot_final<<<16417, 256, 0, stream>>>(coup, u, v, NORM);
}

// Round 5
// 6282.928 us; speedup vs baseline: 2.2198x; 1.2814x over previous
//
#include <hip/hip_runtime.h>
#include <hip/hip_bf16.h>
#include <hip/hip_fp16.h>
#include <cmath>

using bf16 = __hip_bfloat16;
typedef __attribute__((ext_vector_type(8))) short short8;
typedef __attribute__((ext_vector_type(4))) float floatx4;

__device__ __forceinline__ void lds_load16(void* lds, const void* g) {
  __builtin_amdgcn_global_load_lds(
      (const __attribute__((address_space(1))) void*)g,
      (__attribute__((address_space(3))) void*)lds, 16, 0, 0);
}

// ---------------- generic BT GEMM: C[M][N] = scale*(A[M][K] x B[N][K]^T) + bias ----------
struct GemmP {
  const bf16* A; const bf16* B;
  int M, N, K, lda, ldb;
  long sAimg, sAh, sBimg, sBh;
  int ZH, cross;
  float scale;
  const float* bias;
  float* Cf; int ldcf; long sCfImg, sCfH;
  bf16* Cb; int ldcb; long sCbImg, sCbH;
  __half* Ch; int ldch; long sChImg, sChH;
  const float* resid;  // fp32, same indexing as Cf
};

template <int NTILE>  // 128: 4 waves x (64x64); 64: 4 waves x (32x64)
__global__ __launch_bounds__(256, 2)
void gemm_bt(GemmP p) {
  __shared__ __align__(16) bf16 As[128 * 32];
  __shared__ __align__(16) bf16 Bs[NTILE * 32];
  constexpr int MI = (NTILE == 128) ? 4 : 2;
  const int z = blockIdx.z;
  const int imgA = z / p.ZH;
  const int h = z - imgA * p.ZH;
  const int imgB = imgA ^ p.cross;
  const bf16* Ab = p.A + (long)imgA * p.sAimg + (long)h * p.sAh;
  const bf16* Bb = p.B + (long)imgB * p.sBimg + (long)h * p.sBh;
  const int m0 = blockIdx.y * 128, n0 = blockIdx.x * NTILE;
  const int t = threadIdx.x, w = t >> 6, l = t & 63;
  const int lr = l >> 2, lk = (l & 3) * 8;   // staging: row-in-chunk, k-elem offset
  const int fr = l & 15, fk = (l >> 4) * 8;  // fragment: row-in-16tile, k offset

  const bf16* aG0 = Ab + (long)(m0 + w * 16 + lr) * p.lda + lk;
  const bf16* aG1 = aG0 + (long)64 * p.lda;
  const bf16* bG0 = Bb + (long)(n0 + w * 16 + lr) * p.ldb + lk;
  const bf16* bG1 = bG0 + (long)64 * p.ldb;
  bf16* aL0 = &As[w * 16 * 32];
  bf16* aL1 = &As[(w + 4) * 16 * 32];
  bf16* bL0 = &Bs[w * 16 * 32];
  bf16* bL1 = &Bs[(w + 4) * 16 * 32];
  const int wr = (NTILE == 128) ? (w >> 1) * 64 : w * 32;
  const int wc = (NTILE == 128) ? (w & 1) * 64 : 0;

  floatx4 zero4 = {0.f, 0.f, 0.f, 0.f};
  floatx4 acc[MI][4];
#pragma unroll
  for (int i = 0; i < MI; i++)
#pragma unroll
    for (int j = 0; j < 4; j++) acc[i][j] = zero4;

  for (int k0 = 0; k0 < p.K; k0 += 32) {
    lds_load16(aL0, aG0 + k0);
    lds_load16(aL1, aG1 + k0);
    lds_load16(bL0, bG0 + k0);
    if (NTILE == 128) lds_load16(bL1, bG1 + k0);
    __syncthreads();
    short8 af[MI], bfv[4];
#pragma unroll
    for (int i = 0; i < MI; i++)
      af[i] = *(const short8*)&As[(wr + i * 16 + fr) * 32 + fk];
#pragma unroll
    for (int j = 0; j < 4; j++)
      bfv[j] = *(const short8*)&Bs[(wc + j * 16 + fr) * 32 + fk];
#pragma unroll
    for (int i = 0; i < MI; i++)
#pragma unroll
      for (int j = 0; j < 4; j++)
        acc[i][j] = __builtin_amdgcn_mfma_f32_16x16x32_bf16(af[i], bfv[j], acc[i][j], 0, 0, 0);
    __syncthreads();
  }

  // epilogue: D[row][col], col = lane&15, row = (lane>>4)*4 + r  [m89-verified layout]
  const int cl = l & 15, rq = (l >> 4) * 4;
  const long cfBase = (long)imgA * p.sCfImg + (long)h * p.sCfH;
  const long cbBase = (long)imgA * p.sCbImg + (long)h * p.sCbH;
  const long chBase = (long)imgA * p.sChImg + (long)h * p.sChH;
#pragma unroll
  for (int j = 0; j < 4; j++) {
    const int col = n0 + wc + j * 16 + cl;
    if (col >= p.N) continue;
    const float bv = p.bias ? p.bias[col] : 0.f;
#pragma unroll
    for (int i = 0; i < MI; i++) {
#pragma unroll
      for (int r = 0; r < 4; r++) {
        const int row = m0 + wr + i * 16 + rq + r;
        float val = acc[i][j][r] * p.scale + bv;
        if (p.resid) val += p.resid[cfBase + (long)row * p.ldcf + col];
        if (p.Cf) p.Cf[cfBase + (long)row * p.ldcf + col] = val;
        if (p.Cb) p.Cb[cbBase + (long)row * p.ldcb + col] = __float2bfloat16(val);
        if (p.Ch) p.Ch[chBase + (long)row * p.ldch + col] = __float2half(val);
      }
    }
  }
}

// ---------------- elementwise / helper kernels ----------------
__global__ __launch_bounds__(256)
void cvt_f2b(const float* __restrict__ in, bf16* __restrict__ out, long n) {
  long i = (long)blockIdx.x * 256 + threadIdx.x;
  const long stride = (long)gridDim.x * 256;
  for (; i < n; i += stride) out[i] = __float2bfloat16(in[i]);
}

// fused per-layer weight conversion into rotating buffer (5 MB):
// [0:768K) wqkv stacked | [768K:1M) wm(col-permuted) | [1M:2M) w1 | [2M:2.5M) w2
// plus packed qkv bias (1536 floats)
__global__ __launch_bounds__(256)
void cvt_layer(const float* __restrict__ Wq, const float* __restrict__ Wk,
               const float* __restrict__ Wv, const float* __restrict__ Wm,
               const float* __restrict__ W1, const float* __restrict__ W2,
               const float* __restrict__ bq, const float* __restrict__ bk,
               const float* __restrict__ bv,
               int layer, bf16* __restrict__ out, float* __restrict__ bqkv) {
  const long i = (long)blockIdx.x * 256 + threadIdx.x;
  if (i >= 2621440L + 1536) return;
  if (i >= 2621440L) {
    const int j = (int)(i - 2621440L);
    float b;
    if (j < 512) b = bq[layer * 512 + j];
    else if (j < 1024) b = bk[layer * 512 + j - 512];
    else b = bv[layer * 512 + j - 1024];
    bqkv[j] = b;
    return;
  }
  float v;
  if (i < 262144) {
    v = Wq[(long)layer * 262144 + i];
  } else if (i < 524288) {
    v = Wk[(long)layer * 262144 + i - 262144];
  } else if (i < 786432) {
    v = Wv[(long)layer * 262144 + i - 524288];
  } else if (i < 1048576) {
    const long j = i - 786432;
    const int o = (int)(j >> 9), cp = (int)(j & 511);
    v = Wm[(long)layer * 262144 + o * 512 + (cp & 63) * 8 + (cp >> 6)];
  } else if (i < 2097152) {
    v = W1[(long)layer * 1048576 + i - 1048576];
  } else {
    v = W2[(long)layer * 524288 + i - 2097152];
  }
  out[i] = __float2bfloat16(v);
}

__global__ __launch_bounds__(256)
void init_x(const float* __restrict__ d0, const float* __restrict__ d1,
            float* __restrict__ Xf, bf16* __restrict__ Yb) {
  long i = (long)blockIdx.x * 256 + threadIdx.x;
  const long stride = (long)gridDim.x * 256;
  const long n = 8L * 1024 * 512;
  for (; i < n; i += stride) {
    const int d = (int)(i & 511);
    const long nn = i >> 9;  // img*1024 + row
    const int img = (int)(nn >> 10);
    const int row = (int)(nn & 1023);
    const int b = img >> 1, s = img & 1;
    const float v = (s ? d1 : d0)[((long)b * 1024 + row) * 512 + d];
    Xf[i] = v;
    Yb[(nn << 10) + d] = __float2bfloat16(v);
  }
}

// softmax over rows of 1024 fp16 logits, in-place rewrite as bf16 probs (wave per row)
__global__ __launch_bounds__(256)
void softmax_rows(__half* S) {
  const int w = threadIdx.x >> 6, l = threadIdx.x & 63;
  const long row = (long)blockIdx.x * 4 + w;
  __half* p = S + row * 1024;
  float xs[16];
  const __half2* hp = (const __half2*)(p + l * 16);
#pragma unroll
  for (int i = 0; i < 8; i++) {
    float2 f = __half22float2(hp[i]);
    xs[2 * i] = f.x; xs[2 * i + 1] = f.y;
  }
  float mx = xs[0];
#pragma unroll
  for (int i = 1; i < 16; i++) mx = fmaxf(mx, xs[i]);
#pragma unroll
  for (int o = 32; o >= 1; o >>= 1) mx = fmaxf(mx, __shfl_xor(mx, o));
  float s = 0.f;
#pragma unroll
  for (int i = 0; i < 16; i++) { xs[i] = __expf(xs[i] - mx); s += xs[i]; }
#pragma unroll
  for (int o = 32; o >= 1; o >>= 1) s += __shfl_xor(s, o);
  const float inv = 1.f / s;
  bf16* ob = (bf16*)p;
#pragma unroll
  for (int i = 0; i < 16; i++) ob[l * 16 + i] = __float2bfloat16(xs[i] * inv);
}

// transpose [8][1024][512-cols-of-ldi] (2-byte elems) -> [8][512][1024]
__global__ __launch_bounds__(256)
void transpose_2b(const unsigned short* __restrict__ in, int ldi,
                  unsigned short* __restrict__ out) {
  __shared__ unsigned short tile[64][65];
  const int img = blockIdx.z;
  const int m0 = blockIdx.y * 64, c0 = blockIdx.x * 64;
  const int col = threadIdx.x & 63, r0 = threadIdx.x >> 6;
  const unsigned short* ip = in + ((long)img * 1024 + m0) * ldi + c0;
#pragma unroll
  for (int i = 0; i < 16; i++) { int r = r0 + i * 4; tile[r][col] = ip[(long)r * ldi + col]; }
  __syncthreads();
  unsigned short* op = out + ((long)img * 512 + c0) * 1024 + m0;
#pragma unroll
  for (int i = 0; i < 16; i++) { int r = r0 + i * 4; op[(long)r * 1024 + col] = tile[col][r]; }
}

// instance-norm stats: column sums over n per (img, channel); stats pre-zeroed
__global__ __launch_bounds__(256)
void in_stats(const float* __restrict__ T1, float* __restrict__ stats) {
  const int img = blockIdx.z;
  const int c = blockIdx.x * 256 + threadIdx.x;
  const int nb = blockIdx.y;
  const float* p = T1 + ((long)img * 1024 + nb * 128) * 1024 + c;
  float s = 0.f, s2 = 0.f;
#pragma unroll 4
  for (int i = 0; i < 128; i++) { const float x = p[(long)i * 1024]; s += x; s2 += x * x; }
  atomicAdd(&stats[img * 2048 + c], s);
  atomicAdd(&stats[img * 2048 + 1024 + c], s2);
}

__global__ __launch_bounds__(256)
void in_apply(const float* __restrict__ T1, const float* __restrict__ stats,
              bf16* __restrict__ Z) {
  long i = (long)blockIdx.x * 256 + threadIdx.x;
  const long stride = (long)gridDim.x * 256;
  for (; i < 8L * 1024 * 1024; i += stride) {
    const int c = (int)(i & 1023);
    const int img = (int)(i >> 20);
    const float mean = stats[img * 2048 + c] * (1.f / 1024.f);
    const float var = fmaxf(stats[img * 2048 + 1024 + c] * (1.f / 1024.f) - mean * mean, 0.f);
    const float zz = (T1[i] - mean) * rsqrtf(var + 1e-5f);
    Z[i] = __float2bfloat16(fmaxf(zz, 0.f));
  }
}

__global__ __launch_bounds__(256)
void fill_bins(float* C, const float* alpha) {
  const int i = blockIdx.x * 256 + threadIdx.x;
  if (i >= 4 * 1025) return;
  const float a = *alpha;
  const int b = i / 1025, n = i - b * 1025;
  C[((long)b * 1025 + n) * 1025 + 1024] = a;
  C[((long)b * 1025 + 1024) * 1025 + n] = a;
}

// fp32 coupling -> fp16 straight copy + fp16 transpose (for L2-resident sinkhorn)
__global__ __launch_bounds__(256)
void coup_to_fp16(const float* __restrict__ in, __half* __restrict__ outN,
                  __half* __restrict__ outT) {
  __shared__ float tile[32][33];
  const int b = blockIdx.z;
  const int x0 = blockIdx.x * 32, y0 = blockIdx.y * 32;
  const int lx = threadIdx.x & 31, ly = threadIdx.x >> 5;  // ly 0..7
#pragma unroll
  for (int i = 0; i < 4; i++) {
    const int y = ly + i * 8;
    if (y0 + y < 1025 && x0 + lx < 1025) {
      const float vv = in[((long)b * 1025 + y0 + y) * 1025 + x0 + lx];
      tile[y][lx] = vv;
      outN[((long)b * 1025 + y0 + y) * 1025 + x0 + lx] = __float2half(vv);
    }
  }
  __syncthreads();
#pragma unroll
  for (int i = 0; i < 4; i++) {
    const int y = ly + i * 8;
    if (x0 + y < 1025 && y0 + lx < 1025)
      outT[((long)b * 1025 + x0 + y) * 1025 + y0 + lx] = __float2half(tile[lx][y]);
  }
}

// -------- persistent Sinkhorn: 64 blocks x 1024 threads, custom lightweight barrier ------
// Round-5 rewrite of the row LSE: batch 16 independent loads into x[0..15] (one L2
// latency per row instead of 17 serialized), then two-phase max/sum (independent exps)
// instead of the serial online-LSE chain.
#define SK_BLOCKS 64

__global__ __launch_bounds__(1024)
void sinkhorn_pers(const __half* __restrict__ C, const __half* __restrict__ CT,
                   float* __restrict__ u, float* __restrict__ v,
                   unsigned int* __restrict__ ctr,
                   float norm, float logN, int iters) {
  __shared__ float sv[4104];
  const int t = threadIdx.x;
  const int w = t >> 6, l = t & 63;
  const int wid = blockIdx.x * 16 + w;  // 0..1023
  unsigned int barTarget = 0;

  for (int it = 0; it < iters; it++) {
#pragma unroll
    for (int half = 0; half < 2; half++) {
      const float* src = half ? u : v;
      float* dst = half ? v : u;
      const __half* mat = half ? CT : C;
      // stage src (4100 floats) into LDS: 4 unrolled independent agent-loads + tail
      {
        const float s0 = __hip_atomic_load(&src[t], __ATOMIC_RELAXED, __HIP_MEMORY_SCOPE_AGENT);
        const float s1 = __hip_atomic_load(&src[t + 1024], __ATOMIC_RELAXED, __HIP_MEMORY_SCOPE_AGENT);
        const float s2 = __hip_atomic_load(&src[t + 2048], __ATOMIC_RELAXED, __HIP_MEMORY_SCOPE_AGENT);
        const float s3 = __hip_atomic_load(&src[t + 3072], __ATOMIC_RELAXED, __HIP_MEMORY_SCOPE_AGENT);
        float s4 = 0.f;
        if (t < 4) s4 = __hip_atomic_load(&src[t + 4096], __ATOMIC_RELAXED, __HIP_MEMORY_SCOPE_AGENT);
        sv[t] = s0; sv[t + 1024] = s1; sv[t + 2048] = s2; sv[t + 3072] = s3;
        if (t < 4) sv[t + 4096] = s4;
      }
      __syncthreads();
      // each wave: 4 rows (waves 0-3: 5th row). batch-load + two-phase LSE.
#pragma unroll
      for (int rr = 0; rr < 5; rr++) {
        const int gw = wid + rr * 1024;
        if (gw >= 4100) break;
        const int b = gw >> 10 > 3 ? 3 : gw / 1025;  // gw/1025 (gw<4100)
        const int bb = gw / 1025, n = gw - bb * 1025;
        (void)b;
        const __half* row = mat + ((long)bb * 1025 + n) * 1025;
        const float* vv = &sv[bb * 1025];
        float x[16];
#pragma unroll
        for (int i = 0; i < 16; i++)
          x[i] = __half2float(row[l + 64 * i]) + vv[l + 64 * i];
        const float extra = (l == 0) ? (__half2float(row[1024]) + vv[1024]) : -3.0e38f;
        float M = extra;
#pragma unroll
        for (int i = 0; i < 16; i++) M = fmaxf(M, x[i]);
#pragma unroll
        for (int o = 32; o >= 1; o >>= 1) M = fmaxf(M, __shfl_xor(M, o));
        float S = (l == 0) ? __expf(extra - M) : 0.f;
#pragma unroll
        for (int i = 0; i < 16; i++) S += __expf(x[i] - M);
#pragma unroll
        for (int o = 32; o >= 1; o >>= 1) S += __shfl_xor(S, o);
        if (l == 0) {
          const float val = ((n == 1024) ? (logN + norm) : norm) - (M + __logf(S));
          __hip_atomic_store(&dst[gw], val, __ATOMIC_RELAXED, __HIP_MEMORY_SCOPE_AGENT);
        }
      }
      // ---- lightweight device barrier ----
      __syncthreads();  // drains this block's AGENT stores & protects sv reuse
      barTarget += SK_BLOCKS;
      if (t == 0) {
        __hip_atomic_fetch_add(ctr, 1u, __ATOMIC_RELEASE, __HIP_MEMORY_SCOPE_AGENT);
        while (__hip_atomic_load(ctr, __ATOMIC_ACQUIRE, __HIP_MEMORY_SCOPE_AGENT) < barTarget)
          __builtin_amdgcn_s_sleep(1);
      }
      __syncthreads();
    }
  }
}

__global__ __launch_bounds__(256)
void ot_final(float* __restrict__ C, const float* __restrict__ u,
              const float* __restrict__ v, float norm) {
  long i = (long)blockIdx.x * 256 + threadIdx.x;
  if (i >= 4L * 1025 * 1025) return;
  const int b = (int)(i / 1050625);
  const long r = i - (long)b * 1050625;
  const int n = (int)(r / 1025);
  const int m = (int)(r - (long)n * 1025);
  C[i] += u[b * 1025 + n] + v[b * 1025 + m] - norm;
}

// ---------------- host ----------------
extern "C" void kernel_launch(void* const* d_in, const int* in_sizes, int n_in,
                              void* d_out, int out_size, void* d_ws, size_t ws_size,
                              hipStream_t stream) {
  (void)in_sizes; (void)n_in; (void)out_size;
  const float* descs0 = (const float*)d_in[0];
  const float* descs1 = (const float*)d_in[1];
  const float* Wq = (const float*)d_in[2];
  const float* bq = (const float*)d_in[3];
  const float* Wk = (const float*)d_in[4];
  const float* bk = (const float*)d_in[5];
  const float* Wv = (const float*)d_in[6];
  const float* bvv = (const float*)d_in[7];
  const float* Wm = (const float*)d_in[8];
  const float* bm = (const float*)d_in[9];
  const float* W1 = (const float*)d_in[10];
  const float* b1 = (const float*)d_in[11];
  const float* W2 = (const float*)d_in[12];
  const float* b2 = (const float*)d_in[13];
  const float* Wf = (const float*)d_in[14];
  const float* bff = (const float*)d_in[15];
  const float* alpha = (const float*)d_in[16];

  char* ws = (char*)d_ws;
  size_t off = 0;
  auto alloc = [&](size_t bytes) -> void* {
    off = (off + 255) & ~(size_t)255;
    void* p = ws + off;
    off += bytes;
    return p;
  };

  // adaptive attention chunking: full scores buffer needs ~206 MB of ws
  const bool full = ws_size >= ((size_t)210 << 20);
  const int nch = full ? 1 : 4;
  const int chImgs = full ? 8 : 2;
  const size_t scrBytes = full ? ((size_t)chImgs * 8 * 1024 * 1024 * 2)  // 128 MB
                               : 50331648;                               // 48 MB

  bf16* wL = (bf16*)alloc(2621440L * 2);           // rotating per-layer weights (5 MB)
  float* bqkv = (float*)alloc(1536 * 4);
  bf16* WfB = (bf16*)alloc(512L * 512 * 2);
  float* Xf = (float*)alloc(8L * 1024 * 512 * 4);  // fp32 residual stream
  bf16* Yb = (bf16*)alloc(8L * 1024 * 1024 * 2);   // [img][n][1024]: 0:512 x, 512:1024 msg
  bf16* QKVb = (bf16*)alloc(8L * 1024 * 1536 * 2); // [token][1536] q|k|v
  bf16* vchan = (bf16*)alloc(8L * 1024 * 512 * 2); // [img][512ch][1024tok]
  bf16* Ob = (bf16*)alloc(8L * 1024 * 512 * 2);    // attn out [token][512]
  char* SCR = (char*)alloc(scrBytes);              // scores / T1+Zb / Ch+CTh+mproj
  float* stats = (float*)alloc(8L * 2048 * 4);
  float* u = (float*)alloc(4L * 1025 * 4);
  float* v = (float*)alloc(4L * 1025 * 4);
  unsigned int* ctr = (unsigned int*)alloc(256);

  bf16* wqkv = wL;                 // [1536][512]
  bf16* wm = wL + 786432;
  bf16* w1 = wL + 1048576;
  bf16* w2 = wL + 2097152;
  __half* scoresH = (__half*)SCR;  // chunk: chImgs*8*1024*1024 fp16
  bf16* probsB = (bf16*)SCR;
  float* T1 = (float*)SCR;                 // 32 MB
  bf16* Zb = (bf16*)(SCR + 33554432);      // 16 MB
  __half* Ch = (__half*)SCR;               // 8.4 MB fp16 couplings (post-layers)
  __half* CTh = (__half*)(SCR + 8405248);  // 8.4 MB fp16 transposed
  bf16* mproj = (bf16*)(SCR + 33554432);   // 8 MB (post-layers)
  float* coup = (float*)d_out;

  cvt_f2b<<<512, 256, 0, stream>>>(Wf, WfB, 512L * 512);
  init_x<<<4096, 256, 0, stream>>>(descs0, descs1, Xf, Yb);

  auto gemm = [&](int ntile, const bf16* A, const bf16* B, int M, int N, int K,
                  int lda, int ldb, long sAimg, long sAh, long sBimg, long sBh,
                  int Z, int ZH, int cross, float scale, const float* bias,
                  float* Cf, int ldcf, long sCfImg, long sCfH,
                  bf16* Cb, int ldcb, long sCbImg, long sCbH,
                  __half* Ch_, int ldch, long sChImg, long sChH,
                  const float* resid) {
    GemmP p;
    p.A = A; p.B = B; p.M = M; p.N = N; p.K = K; p.lda = lda; p.ldb = ldb;
    p.sAimg = sAimg; p.sAh = sAh; p.sBimg = sBimg; p.sBh = sBh;
    p.ZH = ZH; p.cross = cross; p.scale = scale; p.bias = bias;
    p.Cf = Cf; p.ldcf = ldcf; p.sCfImg = sCfImg; p.sCfH = sCfH;
    p.Cb = Cb; p.ldcb = ldcb; p.sCbImg = sCbImg; p.sCbH = sCbH;
    p.Ch = Ch_; p.ldch = ldch; p.sChImg = sChImg; p.sChH = sChH;
    p.resid = resid;
    dim3 g((unsigned)((N + ntile - 1) / ntile), (unsigned)((M + 127) / 128), (unsigned)Z);
    if (ntile == 128) gemm_bt<128><<<g, 256, 0, stream>>>(p);
    else gemm_bt<64><<<g, 256, 0, stream>>>(p);
  };

  for (int i = 0; i < 12; i++) {
    const int cross = i & 1;  // NAMES = self,cross,self,...
    cvt_layer<<<10247, 256, 0, stream>>>(Wq, Wk, Wv, Wm, W1, W2, bq, bk, bvv, i, wL, bqkv);

    // fused QKV: [8192,1536] = Yb[:, :512] x Wqkv^T
    gemm(128, Yb, wqkv, 8192, 1536, 512, 1024, 512, 0, 0, 0, 0, 1, 1, 0, 1.f, bqkv,
         nullptr, 0, 0, 0, QKVb, 1536, 0, 0, nullptr, 0, 0, 0, nullptr);
    // v channels -> channel-major
    transpose_2b<<<dim3(8, 16, 8), 256, 0, stream>>>((const unsigned short*)(QKVb + 1024),
                                                     1536, (unsigned short*)vchan);
    for (int c = 0; c < nch; c++) {
      const long tokOfs = (long)c * chImgs * 1024 * 1536;
      // scores[limg][h][n][m] = q.k^T / 8  (fp16)
      gemm(128, QKVb + tokOfs, QKVb + tokOfs + 512, 1024, 1024, 64, 1536, 1536,
           1572864, 64, 1572864, 64, chImgs * 8, 8, cross,
           0.125f, nullptr,
           nullptr, 0, 0, 0, nullptr, 0, 0, 0,
           scoresH, 1024, 8L * 1048576, 1048576, nullptr);
      softmax_rows<<<chImgs * 2048, 256, 0, stream>>>(scoresH);
      // O[limg][n][h*64+dh] = probs x V  (NTILE=64: no wasted MFMA on N=64)
      gemm(64, probsB, vchan + (long)c * chImgs * 524288, 1024, 64, 1024, 1024, 1024,
           8L * 1048576, 1048576, 524288, 65536, chImgs * 8, 8, cross,
           1.f, nullptr,
           nullptr, 0, 0, 0, Ob + (long)c * chImgs * 524288, 512, 524288, 64,
           nullptr, 0, 0, 0, nullptr);
    }
    // msg -> Yb[:, 512:1024]  (wm pre-permuted for head-merge order)
    gemm(128, Ob, wm, 8192, 512, 512, 512, 512, 0, 0, 0, 0, 1, 1, 0, 1.f, bm + i * 512,
         nullptr, 0, 0, 0, Yb + 512, 1024, 0, 0, nullptr, 0, 0, 0, nullptr);
    // T1 = W1 x [x; msg] + b1 (fp32)
    gemm(128, Yb, w1, 8192, 1024, 1024, 1024, 1024, 0, 0, 0, 0, 1, 1, 0, 1.f, b1 + i * 1024,
         T1, 1024, 0, 0, nullptr, 0, 0, 0, nullptr, 0, 0, 0, nullptr);
    hipMemsetAsync(stats, 0, 8L * 2048 * 4, stream);
    in_stats<<<dim3(4, 8, 8), 256, 0, stream>>>(T1, stats);
    in_apply<<<8192, 256, 0, stream>>>(T1, stats, Zb);
    // x += W2 z + b2 : fp32 residual into Xf, bf16 mirror into Yb[:, :512]
    gemm(128, Zb, w2, 8192, 512, 1024, 1024, 1024, 0, 0, 0, 0, 1, 1, 0, 1.f, b2 + i * 512,
         Xf, 512, 0, 0, Yb, 1024, 0, 0, nullptr, 0, 0, 0, Xf);
  }

  // final projection + score matrix into d_out
  gemm(128, Yb, WfB, 8192, 512, 512, 1024, 512, 0, 0, 0, 0, 1, 1, 0, 1.f, bff,
       nullptr, 0, 0, 0, mproj, 512, 0, 0, nullptr, 0, 0, 0, nullptr);
  gemm(128, mproj, mproj + 524288, 1024, 1024, 512, 512, 512,
       1048576, 0, 1048576, 0, 4, 1, 0,
       0.044194173824159216f, nullptr,
       coup, 1025, 1050625, 0, nullptr, 0, 0, 0, nullptr, 0, 0, 0, nullptr);
  fill_bins<<<17, 256, 0, stream>>>(coup, alpha);
  coup_to_fp16<<<dim3(33, 33, 4), 256, 0, stream>>>(coup, Ch, CTh);

  hipMemsetAsync(u, 0, 4L * 1025 * 4, stream);
  hipMemsetAsync(v, 0, 4L * 1025 * 4, stream);
  hipMemsetAsync(ctr, 0, 256, stream);
  const float NORM = -logf(2048.f);
  const float LOGN = logf(1024.f);
  int iters = 100;
  void* args[] = {(void*)&Ch, (void*)&CTh, (void*)&u, (void*)&v, (void*)&ctr,
                  (void*)&NORM, (void*)&LOGN, (void*)&iters};
  hipLaunchCooperativeKernel((void*)sinkhorn_pers, dim3(SK_BLOCKS), dim3(1024), args, 0, stream);
  ot_final<<<16417, 256, 0, stream>>>(coup, u, v, NORM);
}

// Round 6
// 5758.832 us; speedup vs baseline: 2.4218x; 1.0910x over previous
//
#include <hip/hip_runtime.h>
#include <hip/hip_bf16.h>
#include <hip/hip_fp16.h>
#include <cmath>

using bf16 = __hip_bfloat16;
typedef __attribute__((ext_vector_type(8))) short short8;
typedef __attribute__((ext_vector_type(4))) float floatx4;

__device__ __forceinline__ void lds_load16(void* lds, const void* g) {
  __builtin_amdgcn_global_load_lds(
      (const __attribute__((address_space(1))) void*)g,
      (__attribute__((address_space(3))) void*)lds, 16, 0, 0);
}

// ---------------- generic BT GEMM: C[M][N] = scale*(A[M][K] x B[N][K]^T) + bias ----------
struct GemmP {
  const bf16* A; const bf16* B;
  int M, N, K, lda, ldb;
  long sAimg, sAh, sBimg, sBh;
  int ZH, cross;
  float scale;
  const float* bias;
  float* Cf; int ldcf; long sCfImg, sCfH;
  bf16* Cb; int ldcb; long sCbImg, sCbH;
  __half* Ch; int ldch; long sChImg, sChH;
  const float* resid;  // fp32, same indexing as Cf
};

template <int NTILE>  // 128: 4 waves x (64x64); 64: 4 waves x (32x64)
__global__ __launch_bounds__(256, 2)
void gemm_bt(GemmP p) {
  __shared__ __align__(16) bf16 As[128 * 32];
  __shared__ __align__(16) bf16 Bs[NTILE * 32];
  constexpr int MI = (NTILE == 128) ? 4 : 2;
  const int z = blockIdx.z;
  const int imgA = z / p.ZH;
  const int h = z - imgA * p.ZH;
  const int imgB = imgA ^ p.cross;
  const bf16* Ab = p.A + (long)imgA * p.sAimg + (long)h * p.sAh;
  const bf16* Bb = p.B + (long)imgB * p.sBimg + (long)h * p.sBh;
  const int m0 = blockIdx.y * 128, n0 = blockIdx.x * NTILE;
  const int t = threadIdx.x, w = t >> 6, l = t & 63;
  const int lr = l >> 2, lk = (l & 3) * 8;   // staging: row-in-chunk, k-elem offset
  const int fr = l & 15, fk = (l >> 4) * 8;  // fragment: row-in-16tile, k offset

  const bf16* aG0 = Ab + (long)(m0 + w * 16 + lr) * p.lda + lk;
  const bf16* aG1 = aG0 + (long)64 * p.lda;
  const bf16* bG0 = Bb + (long)(n0 + w * 16 + lr) * p.ldb + lk;
  const bf16* bG1 = bG0 + (long)64 * p.ldb;
  bf16* aL0 = &As[w * 16 * 32];
  bf16* aL1 = &As[(w + 4) * 16 * 32];
  bf16* bL0 = &Bs[w * 16 * 32];
  bf16* bL1 = &Bs[(w + 4) * 16 * 32];
  const int wr = (NTILE == 128) ? (w >> 1) * 64 : w * 32;
  const int wc = (NTILE == 128) ? (w & 1) * 64 : 0;

  floatx4 zero4 = {0.f, 0.f, 0.f, 0.f};
  floatx4 acc[MI][4];
#pragma unroll
  for (int i = 0; i < MI; i++)
#pragma unroll
    for (int j = 0; j < 4; j++) acc[i][j] = zero4;

  for (int k0 = 0; k0 < p.K; k0 += 32) {
    lds_load16(aL0, aG0 + k0);
    lds_load16(aL1, aG1 + k0);
    lds_load16(bL0, bG0 + k0);
    if (NTILE == 128) lds_load16(bL1, bG1 + k0);
    __syncthreads();
    short8 af[MI], bfv[4];
#pragma unroll
    for (int i = 0; i < MI; i++)
      af[i] = *(const short8*)&As[(wr + i * 16 + fr) * 32 + fk];
#pragma unroll
    for (int j = 0; j < 4; j++)
      bfv[j] = *(const short8*)&Bs[(wc + j * 16 + fr) * 32 + fk];
#pragma unroll
    for (int i = 0; i < MI; i++)
#pragma unroll
      for (int j = 0; j < 4; j++)
        acc[i][j] = __builtin_amdgcn_mfma_f32_16x16x32_bf16(af[i], bfv[j], acc[i][j], 0, 0, 0);
    __syncthreads();
  }

  // epilogue: D[row][col], col = lane&15, row = (lane>>4)*4 + r  [m89-verified layout]
  const int cl = l & 15, rq = (l >> 4) * 4;
  const long cfBase = (long)imgA * p.sCfImg + (long)h * p.sCfH;
  const long cbBase = (long)imgA * p.sCbImg + (long)h * p.sCbH;
  const long chBase = (long)imgA * p.sChImg + (long)h * p.sChH;
#pragma unroll
  for (int j = 0; j < 4; j++) {
    const int col = n0 + wc + j * 16 + cl;
    if (col >= p.N) continue;
    const float bv = p.bias ? p.bias[col] : 0.f;
#pragma unroll
    for (int i = 0; i < MI; i++) {
#pragma unroll
      for (int r = 0; r < 4; r++) {
        const int row = m0 + wr + i * 16 + rq + r;
        float val = acc[i][j][r] * p.scale + bv;
        if (p.resid) val += p.resid[cfBase + (long)row * p.ldcf + col];
        if (p.Cf) p.Cf[cfBase + (long)row * p.ldcf + col] = val;
        if (p.Cb) p.Cb[cbBase + (long)row * p.ldcb + col] = __float2bfloat16(val);
        if (p.Ch) p.Ch[chBase + (long)row * p.ldch + col] = __float2half(val);
      }
    }
  }
}

// ---------------- elementwise / helper kernels ----------------
__global__ __launch_bounds__(256)
void cvt_f2b(const float* __restrict__ in, bf16* __restrict__ out, long n) {
  long i = (long)blockIdx.x * 256 + threadIdx.x;
  const long stride = (long)gridDim.x * 256;
  for (; i < n; i += stride) out[i] = __float2bfloat16(in[i]);
}

// fused per-layer weight conversion into rotating buffer (5 MB):
// [0:768K) wqkv stacked | [768K:1M) wm(col-permuted) | [1M:2M) w1 | [2M:2.5M) w2
// plus packed qkv bias (1536 floats)
__global__ __launch_bounds__(256)
void cvt_layer(const float* __restrict__ Wq, const float* __restrict__ Wk,
               const float* __restrict__ Wv, const float* __restrict__ Wm,
               const float* __restrict__ W1, const float* __restrict__ W2,
               const float* __restrict__ bq, const float* __restrict__ bk,
               const float* __restrict__ bv,
               int layer, bf16* __restrict__ out, float* __restrict__ bqkv) {
  const long i = (long)blockIdx.x * 256 + threadIdx.x;
  if (i >= 2621440L + 1536) return;
  if (i >= 2621440L) {
    const int j = (int)(i - 2621440L);
    float b;
    if (j < 512) b = bq[layer * 512 + j];
    else if (j < 1024) b = bk[layer * 512 + j - 512];
    else b = bv[layer * 512 + j - 1024];
    bqkv[j] = b;
    return;
  }
  float v;
  if (i < 262144) {
    v = Wq[(long)layer * 262144 + i];
  } else if (i < 524288) {
    v = Wk[(long)layer * 262144 + i - 262144];
  } else if (i < 786432) {
    v = Wv[(long)layer * 262144 + i - 524288];
  } else if (i < 1048576) {
    const long j = i - 786432;
    const int o = (int)(j >> 9), cp = (int)(j & 511);
    v = Wm[(long)layer * 262144 + o * 512 + (cp & 63) * 8 + (cp >> 6)];
  } else if (i < 2097152) {
    v = W1[(long)layer * 1048576 + i - 1048576];
  } else {
    v = W2[(long)layer * 524288 + i - 2097152];
  }
  out[i] = __float2bfloat16(v);
}

__global__ __launch_bounds__(256)
void init_x(const float* __restrict__ d0, const float* __restrict__ d1,
            float* __restrict__ Xf, bf16* __restrict__ Yb) {
  long i = (long)blockIdx.x * 256 + threadIdx.x;
  const long stride = (long)gridDim.x * 256;
  const long n = 8L * 1024 * 512;
  for (; i < n; i += stride) {
    const int d = (int)(i & 511);
    const long nn = i >> 9;  // img*1024 + row
    const int img = (int)(nn >> 10);
    const int row = (int)(nn & 1023);
    const int b = img >> 1, s = img & 1;
    const float v = (s ? d1 : d0)[((long)b * 1024 + row) * 512 + d];
    Xf[i] = v;
    Yb[(nn << 10) + d] = __float2bfloat16(v);
  }
}

// softmax over rows of 1024 fp16 logits, in-place rewrite as bf16 probs (wave per row)
__global__ __launch_bounds__(256)
void softmax_rows(__half* S) {
  const int w = threadIdx.x >> 6, l = threadIdx.x & 63;
  const long row = (long)blockIdx.x * 4 + w;
  __half* p = S + row * 1024;
  float xs[16];
  const __half2* hp = (const __half2*)(p + l * 16);
#pragma unroll
  for (int i = 0; i < 8; i++) {
    float2 f = __half22float2(hp[i]);
    xs[2 * i] = f.x; xs[2 * i + 1] = f.y;
  }
  float mx = xs[0];
#pragma unroll
  for (int i = 1; i < 16; i++) mx = fmaxf(mx, xs[i]);
#pragma unroll
  for (int o = 32; o >= 1; o >>= 1) mx = fmaxf(mx, __shfl_xor(mx, o));
  float s = 0.f;
#pragma unroll
  for (int i = 0; i < 16; i++) { xs[i] = __expf(xs[i] - mx); s += xs[i]; }
#pragma unroll
  for (int o = 32; o >= 1; o >>= 1) s += __shfl_xor(s, o);
  const float inv = 1.f / s;
  bf16* ob = (bf16*)p;
#pragma unroll
  for (int i = 0; i < 16; i++) ob[l * 16 + i] = __float2bfloat16(xs[i] * inv);
}

// transpose [8][1024][512-cols-of-ldi] (2-byte elems) -> [8][512][1024]
__global__ __launch_bounds__(256)
void transpose_2b(const unsigned short* __restrict__ in, int ldi,
                  unsigned short* __restrict__ out) {
  __shared__ unsigned short tile[64][65];
  const int img = blockIdx.z;
  const int m0 = blockIdx.y * 64, c0 = blockIdx.x * 64;
  const int col = threadIdx.x & 63, r0 = threadIdx.x >> 6;
  const unsigned short* ip = in + ((long)img * 1024 + m0) * ldi + c0;
#pragma unroll
  for (int i = 0; i < 16; i++) { int r = r0 + i * 4; tile[r][col] = ip[(long)r * ldi + col]; }
  __syncthreads();
  unsigned short* op = out + ((long)img * 512 + c0) * 1024 + m0;
#pragma unroll
  for (int i = 0; i < 16; i++) { int r = r0 + i * 4; op[(long)r * 1024 + col] = tile[col][r]; }
}

// instance-norm stats: column sums over n per (img, channel); stats pre-zeroed
__global__ __launch_bounds__(256)
void in_stats(const float* __restrict__ T1, float* __restrict__ stats) {
  const int img = blockIdx.z;
  const int c = blockIdx.x * 256 + threadIdx.x;
  const int nb = blockIdx.y;
  const float* p = T1 + ((long)img * 1024 + nb * 128) * 1024 + c;
  float s = 0.f, s2 = 0.f;
#pragma unroll 4
  for (int i = 0; i < 128; i++) { const float x = p[(long)i * 1024]; s += x; s2 += x * x; }
  atomicAdd(&stats[img * 2048 + c], s);
  atomicAdd(&stats[img * 2048 + 1024 + c], s2);
}

__global__ __launch_bounds__(256)
void in_apply(const float* __restrict__ T1, const float* __restrict__ stats,
              bf16* __restrict__ Z) {
  long i = (long)blockIdx.x * 256 + threadIdx.x;
  const long stride = (long)gridDim.x * 256;
  for (; i < 8L * 1024 * 1024; i += stride) {
    const int c = (int)(i & 1023);
    const int img = (int)(i >> 20);
    const float mean = stats[img * 2048 + c] * (1.f / 1024.f);
    const float var = fmaxf(stats[img * 2048 + 1024 + c] * (1.f / 1024.f) - mean * mean, 0.f);
    const float zz = (T1[i] - mean) * rsqrtf(var + 1e-5f);
    Z[i] = __float2bfloat16(fmaxf(zz, 0.f));
  }
}

__global__ __launch_bounds__(256)
void fill_bins(float* C, const float* alpha) {
  const int i = blockIdx.x * 256 + threadIdx.x;
  if (i >= 4 * 1025) return;
  const float a = *alpha;
  const int b = i / 1025, n = i - b * 1025;
  C[((long)b * 1025 + n) * 1025 + 1024] = a;
  C[((long)b * 1025 + 1024) * 1025 + n] = a;
}

// fp32 coupling -> fp16 straight copy + fp16 transpose (for L2-resident sinkhorn)
__global__ __launch_bounds__(256)
void coup_to_fp16(const float* __restrict__ in, __half* __restrict__ outN,
                  __half* __restrict__ outT) {
  __shared__ float tile[32][33];
  const int b = blockIdx.z;
  const int x0 = blockIdx.x * 32, y0 = blockIdx.y * 32;
  const int lx = threadIdx.x & 31, ly = threadIdx.x >> 5;  // ly 0..7
#pragma unroll
  for (int i = 0; i < 4; i++) {
    const int y = ly + i * 8;
    if (y0 + y < 1025 && x0 + lx < 1025) {
      const float vv = in[((long)b * 1025 + y0 + y) * 1025 + x0 + lx];
      tile[y][lx] = vv;
      outN[((long)b * 1025 + y0 + y) * 1025 + x0 + lx] = __float2half(vv);
    }
  }
  __syncthreads();
#pragma unroll
  for (int i = 0; i < 4; i++) {
    const int y = ly + i * 8;
    if (x0 + y < 1025 && y0 + lx < 1025)
      outT[((long)b * 1025 + x0 + y) * 1025 + y0 + lx] = __float2half(tile[lx][y]);
  }
}

// -------- persistent Sinkhorn: 256 blocks x 1024 threads (FULL chip), custom barrier ----
// Round-6: r5 showed 38% VALU-busy on only 64 active CUs (compute-throughput-bound).
// 256 blocks -> 4096 waves = 1 row/wave (4 waves take a 2nd row). Per-block L2 slice
// 64 KB (2 MB/XCD, resident). Barrier: 256 arrivals on one LLC line; RELAXED spin +
// one ACQUIRE on exit.
#define SK_BLOCKS 256

__global__ __launch_bounds__(1024)
void sinkhorn_pers(const __half* __restrict__ C, const __half* __restrict__ CT,
                   float* __restrict__ u, float* __restrict__ v,
                   unsigned int* __restrict__ ctr,
                   float norm, float logN, int iters) {
  __shared__ float sv[4104];
  const int t = threadIdx.x;
  const int w = t >> 6, l = t & 63;
  const int wid = blockIdx.x * 16 + w;  // 0..4095
  unsigned int barTarget = 0;

  for (int it = 0; it < iters; it++) {
#pragma unroll
    for (int half = 0; half < 2; half++) {
      const float* src = half ? u : v;
      float* dst = half ? v : u;
      const __half* mat = half ? CT : C;
      // stage src (4100 floats) into LDS: 4 unrolled independent agent-loads + tail
      {
        const float s0 = __hip_atomic_load(&src[t], __ATOMIC_RELAXED, __HIP_MEMORY_SCOPE_AGENT);
        const float s1 = __hip_atomic_load(&src[t + 1024], __ATOMIC_RELAXED, __HIP_MEMORY_SCOPE_AGENT);
        const float s2 = __hip_atomic_load(&src[t + 2048], __ATOMIC_RELAXED, __HIP_MEMORY_SCOPE_AGENT);
        const float s3 = __hip_atomic_load(&src[t + 3072], __ATOMIC_RELAXED, __HIP_MEMORY_SCOPE_AGENT);
        float s4 = 0.f;
        if (t < 4) s4 = __hip_atomic_load(&src[t + 4096], __ATOMIC_RELAXED, __HIP_MEMORY_SCOPE_AGENT);
        sv[t] = s0; sv[t + 1024] = s1; sv[t + 2048] = s2; sv[t + 3072] = s3;
        if (t < 4) sv[t + 4096] = s4;
      }
      __syncthreads();
      // one row per wave (waves 0-3 of block 0..3 pattern: wid<4 takes row 4096+wid)
#pragma unroll
      for (int rr = 0; rr < 2; rr++) {
        const int gw = (rr == 0) ? wid : (4096 + wid);
        if (rr == 1 && wid >= 4) break;
        const int bb = gw / 1025, n = gw - bb * 1025;
        const __half* row = mat + ((long)bb * 1025 + n) * 1025;
        const float* vv = &sv[bb * 1025];
        float x[16];
#pragma unroll
        for (int i = 0; i < 16; i++)
          x[i] = __half2float(row[l + 64 * i]) + vv[l + 64 * i];
        const float extra = (l == 0) ? (__half2float(row[1024]) + vv[1024]) : -3.0e38f;
        float M = extra;
#pragma unroll
        for (int i = 0; i < 16; i++) M = fmaxf(M, x[i]);
#pragma unroll
        for (int o = 32; o >= 1; o >>= 1) M = fmaxf(M, __shfl_xor(M, o));
        float S = (l == 0) ? __expf(extra - M) : 0.f;
#pragma unroll
        for (int i = 0; i < 16; i++) S += __expf(x[i] - M);
#pragma unroll
        for (int o = 32; o >= 1; o >>= 1) S += __shfl_xor(S, o);
        if (l == 0) {
          const float val = ((n == 1024) ? (logN + norm) : norm) - (M + __logf(S));
          __hip_atomic_store(&dst[gw], val, __ATOMIC_RELAXED, __HIP_MEMORY_SCOPE_AGENT);
        }
      }
      // ---- lightweight device barrier (256 arrivals) ----
      __syncthreads();  // drains this block's AGENT stores & protects sv reuse
      barTarget += SK_BLOCKS;
      if (t == 0) {
        __hip_atomic_fetch_add(ctr, 1u, __ATOMIC_RELEASE, __HIP_MEMORY_SCOPE_AGENT);
        while (__hip_atomic_load(ctr, __ATOMIC_RELAXED, __HIP_MEMORY_SCOPE_AGENT) < barTarget)
          __builtin_amdgcn_s_sleep(1);
        (void)__hip_atomic_load(ctr, __ATOMIC_ACQUIRE, __HIP_MEMORY_SCOPE_AGENT);
      }
      __syncthreads();
    }
  }
}

__global__ __launch_bounds__(256)
void ot_final(float* __restrict__ C, const float* __restrict__ u,
              const float* __restrict__ v, float norm) {
  long i = (long)blockIdx.x * 256 + threadIdx.x;
  if (i >= 4L * 1025 * 1025) return;
  const int b = (int)(i / 1050625);
  const long r = i - (long)b * 1050625;
  const int n = (int)(r / 1025);
  const int m = (int)(r - (long)n * 1025);
  C[i] += u[b * 1025 + n] + v[b * 1025 + m] - norm;
}

// ---------------- host ----------------
extern "C" void kernel_launch(void* const* d_in, const int* in_sizes, int n_in,
                              void* d_out, int out_size, void* d_ws, size_t ws_size,
                              hipStream_t stream) {
  (void)in_sizes; (void)n_in; (void)out_size;
  const float* descs0 = (const float*)d_in[0];
  const float* descs1 = (const float*)d_in[1];
  const float* Wq = (const float*)d_in[2];
  const float* bq = (const float*)d_in[3];
  const float* Wk = (const float*)d_in[4];
  const float* bk = (const float*)d_in[5];
  const float* Wv = (const float*)d_in[6];
  const float* bvv = (const float*)d_in[7];
  const float* Wm = (const float*)d_in[8];
  const float* bm = (const float*)d_in[9];
  const float* W1 = (const float*)d_in[10];
  const float* b1 = (const float*)d_in[11];
  const float* W2 = (const float*)d_in[12];
  const float* b2 = (const float*)d_in[13];
  const float* Wf = (const float*)d_in[14];
  const float* bff = (const float*)d_in[15];
  const float* alpha = (const float*)d_in[16];

  char* ws = (char*)d_ws;
  size_t off = 0;
  auto alloc = [&](size_t bytes) -> void* {
    off = (off + 255) & ~(size_t)255;
    void* p = ws + off;
    off += bytes;
    return p;
  };

  // adaptive attention chunking: full scores buffer needs ~206 MB of ws
  const bool full = ws_size >= ((size_t)210 << 20);
  const int nch = full ? 1 : 4;
  const int chImgs = full ? 8 : 2;
  const size_t scrBytes = full ? ((size_t)chImgs * 8 * 1024 * 1024 * 2)  // 128 MB
                               : 50331648;                               // 48 MB

  bf16* wL = (bf16*)alloc(2621440L * 2);           // rotating per-layer weights (5 MB)
  float* bqkv = (float*)alloc(1536 * 4);
  bf16* WfB = (bf16*)alloc(512L * 512 * 2);
  float* Xf = (float*)alloc(8L * 1024 * 512 * 4);  // fp32 residual stream
  bf16* Yb = (bf16*)alloc(8L * 1024 * 1024 * 2);   // [img][n][1024]: 0:512 x, 512:1024 msg
  bf16* QKVb = (bf16*)alloc(8L * 1024 * 1536 * 2); // [token][1536] q|k|v
  bf16* vchan = (bf16*)alloc(8L * 1024 * 512 * 2); // [img][512ch][1024tok]
  bf16* Ob = (bf16*)alloc(8L * 1024 * 512 * 2);    // attn out [token][512]
  char* SCR = (char*)alloc(scrBytes);              // scores / T1+Zb / Ch+CTh+mproj
  float* stats = (float*)alloc(8L * 2048 * 4);
  float* u = (float*)alloc(4L * 1025 * 4);
  float* v = (float*)alloc(4L * 1025 * 4);
  unsigned int* ctr = (unsigned int*)alloc(256);

  bf16* wqkv = wL;                 // [1536][512]
  bf16* wm = wL + 786432;
  bf16* w1 = wL + 1048576;
  bf16* w2 = wL + 2097152;
  __half* scoresH = (__half*)SCR;  // chunk: chImgs*8*1024*1024 fp16
  bf16* probsB = (bf16*)SCR;
  float* T1 = (float*)SCR;                 // 32 MB
  bf16* Zb = (bf16*)(SCR + 33554432);      // 16 MB
  __half* Ch = (__half*)SCR;               // 8.4 MB fp16 couplings (post-layers)
  __half* CTh = (__half*)(SCR + 8405248);  // 8.4 MB fp16 transposed
  bf16* mproj = (bf16*)(SCR + 33554432);   // 8 MB (post-layers)
  float* coup = (float*)d_out;

  cvt_f2b<<<512, 256, 0, stream>>>(Wf, WfB, 512L * 512);
  init_x<<<4096, 256, 0, stream>>>(descs0, descs1, Xf, Yb);

  auto gemm = [&](int ntile, const bf16* A, const bf16* B, int M, int N, int K,
                  int lda, int ldb, long sAimg, long sAh, long sBimg, long sBh,
                  int Z, int ZH, int cross, float scale, const float* bias,
                  float* Cf, int ldcf, long sCfImg, long sCfH,
                  bf16* Cb, int ldcb, long sCbImg, long sCbH,
                  __half* Ch_, int ldch, long sChImg, long sChH,
                  const float* resid) {
    GemmP p;
    p.A = A; p.B = B; p.M = M; p.N = N; p.K = K; p.lda = lda; p.ldb = ldb;
    p.sAimg = sAimg; p.sAh = sAh; p.sBimg = sBimg; p.sBh = sBh;
    p.ZH = ZH; p.cross = cross; p.scale = scale; p.bias = bias;
    p.Cf = Cf; p.ldcf = ldcf; p.sCfImg = sCfImg; p.sCfH = sCfH;
    p.Cb = Cb; p.ldcb = ldcb; p.sCbImg = sCbImg; p.sCbH = sCbH;
    p.Ch = Ch_; p.ldch = ldch; p.sChImg = sChImg; p.sChH = sChH;
    p.resid = resid;
    dim3 g((unsigned)((N + ntile - 1) / ntile), (unsigned)((M + 127) / 128), (unsigned)Z);
    if (ntile == 128) gemm_bt<128><<<g, 256, 0, stream>>>(p);
    else gemm_bt<64><<<g, 256, 0, stream>>>(p);
  };

  for (int i = 0; i < 12; i++) {
    const int cross = i & 1;  // NAMES = self,cross,self,...
    cvt_layer<<<10247, 256, 0, stream>>>(Wq, Wk, Wv, Wm, W1, W2, bq, bk, bvv, i, wL, bqkv);

    // fused QKV: [8192,1536] = Yb[:, :512] x Wqkv^T
    gemm(128, Yb, wqkv, 8192, 1536, 512, 1024, 512, 0, 0, 0, 0, 1, 1, 0, 1.f, bqkv,
         nullptr, 0, 0, 0, QKVb, 1536, 0, 0, nullptr, 0, 0, 0, nullptr);
    // v channels -> channel-major
    transpose_2b<<<dim3(8, 16, 8), 256, 0, stream>>>((const unsigned short*)(QKVb + 1024),
                                                     1536, (unsigned short*)vchan);
    for (int c = 0; c < nch; c++) {
      const long tokOfs = (long)c * chImgs * 1024 * 1536;
      // scores[limg][h][n][m] = q.k^T / 8  (fp16)
      gemm(128, QKVb + tokOfs, QKVb + tokOfs + 512, 1024, 1024, 64, 1536, 1536,
           1572864, 64, 1572864, 64, chImgs * 8, 8, cross,
           0.125f, nullptr,
           nullptr, 0, 0, 0, nullptr, 0, 0, 0,
           scoresH, 1024, 8L * 1048576, 1048576, nullptr);
      softmax_rows<<<chImgs * 2048, 256, 0, stream>>>(scoresH);
      // O[limg][n][h*64+dh] = probs x V  (NTILE=64: no wasted MFMA on N=64)
      gemm(64, probsB, vchan + (long)c * chImgs * 524288, 1024, 64, 1024, 1024, 1024,
           8L * 1048576, 1048576, 524288, 65536, chImgs * 8, 8, cross,
           1.f, nullptr,
           nullptr, 0, 0, 0, Ob + (long)c * chImgs * 524288, 512, 524288, 64,
           nullptr, 0, 0, 0, nullptr);
    }
    // msg -> Yb[:, 512:1024]  (wm pre-permuted for head-merge order)
    gemm(128, Ob, wm, 8192, 512, 512, 512, 512, 0, 0, 0, 0, 1, 1, 0, 1.f, bm + i * 512,
         nullptr, 0, 0, 0, Yb + 512, 1024, 0, 0, nullptr, 0, 0, 0, nullptr);
    // T1 = W1 x [x; msg] + b1 (fp32)
    gemm(128, Yb, w1, 8192, 1024, 1024, 1024, 1024, 0, 0, 0, 0, 1, 1, 0, 1.f, b1 + i * 1024,
         T1, 1024, 0, 0, nullptr, 0, 0, 0, nullptr, 0, 0, 0, nullptr);
    hipMemsetAsync(stats, 0, 8L * 2048 * 4, stream);
    in_stats<<<dim3(4, 8, 8), 256, 0, stream>>>(T1, stats);
    in_apply<<<8192, 256, 0, stream>>>(T1, stats, Zb);
    // x += W2 z + b2 : fp32 residual into Xf, bf16 mirror into Yb[:, :512]
    gemm(128, Zb, w2, 8192, 512, 1024, 1024, 1024, 0, 0, 0, 0, 1, 1, 0, 1.f, b2 + i * 512,
         Xf, 512, 0, 0, Yb, 1024, 0, 0, nullptr, 0, 0, 0, Xf);
  }

  // final projection + score matrix into d_out
  gemm(128, Yb, WfB, 8192, 512, 512, 1024, 512, 0, 0, 0, 0, 1, 1, 0, 1.f, bff,
       nullptr, 0, 0, 0, mproj, 512, 0, 0, nullptr, 0, 0, 0, nullptr);
  gemm(128, mproj, mproj + 524288, 1024, 1024, 512, 512, 512,
       1048576, 0, 1048576, 0, 4, 1, 0,
       0.044194173824159216f, nullptr,
       coup, 1025, 1050625, 0, nullptr, 0, 0, 0, nullptr, 0, 0, 0, nullptr);
  fill_bins<<<17, 256, 0, stream>>>(coup, alpha);
  coup_to_fp16<<<dim3(33, 33, 4), 256, 0, stream>>>(coup, Ch, CTh);

  hipMemsetAsync(u, 0, 4L * 1025 * 4, stream);
  hipMemsetAsync(v, 0, 4L * 1025 * 4, stream);
  hipMemsetAsync(ctr, 0, 256, stream);
  const float NORM = -logf(2048.f);
  const float LOGN = logf(1024.f);
  int iters = 100;
  void* args[] = {(void*)&Ch, (void*)&CTh, (void*)&u, (void*)&v, (void*)&ctr,
                  (void*)&NORM, (void*)&LOGN, (void*)&iters};
  hipLaunchCooperativeKernel((void*)sinkhorn_pers, dim3(SK_BLOCKS), dim3(1024), args, 0, stream);
  ot_final<<<16417, 256, 0, stream>>>(coup, u, v, NORM);
}